// Round 6
// baseline (1925.051 us; speedup 1.0000x reference)
//
#include <hip/hip_runtime.h>

#define S_ 2048
#define E_ 1024
#define H_ 16
#define D_ 64
#define HB_ 204
#define RB_ 204
#define CB_ 408
#define NSCAN_ (S_ - CB_)
#define PEN_ 0.99f
#define NEGINF (-__builtin_huge_valf())
#define POSINF (__builtin_huge_valf())

typedef unsigned short u16;
typedef unsigned int u32;
typedef unsigned int u32x4 __attribute__((ext_vector_type(4)));

__device__ __forceinline__ float bf2f(u16 u) {
    union { u32 u; float f; } a; a.u = ((u32)u) << 16; return a.f;
}
__device__ __forceinline__ u16 f2bf(float f) {
    union { float f; u32 u; } a; a.f = f;
    u32 r = (a.u + 0x7FFFu + ((a.u >> 16) & 1u)) >> 16;
    return (u16)r;
}

// ---------------------------------------------------------------------------
// Wave64 reductions via DPP.
// wsum64 / wsum64_63: sum (broadcast / lane-63-valid).
// wmind64: key-only f64 min (lane 63). wminp64: f64 min + f32 payload (lane 63).
// ---------------------------------------------------------------------------
#define DPPF(ID, V, CTRL, RMASK) \
    __int_as_float(__builtin_amdgcn_update_dpp(__float_as_int(ID), __float_as_int(V), CTRL, RMASK, 0xf, false))

__device__ __forceinline__ float wsum64_63(float v) {
    float t;
    t = DPPF(0.f, v, 0x111, 0xf); v += t;
    t = DPPF(0.f, v, 0x112, 0xf); v += t;
    t = DPPF(0.f, v, 0x114, 0xf); v += t;
    t = DPPF(0.f, v, 0x118, 0xf); v += t;
    t = DPPF(0.f, v, 0x142, 0xa); v += t;
    t = DPPF(0.f, v, 0x143, 0xc); v += t;
    return v;                        // lane 63 holds the wave total
}
__device__ __forceinline__ float wsum64(float v) {
    v = wsum64_63(v);
    return __int_as_float(__builtin_amdgcn_readlane(__float_as_int(v), 63));
}
template <int CTRL, int RMASK>
__device__ __forceinline__ double dmin_step(double v) {
    const int lo = __double2loint(v), hi = __double2hiint(v);
    const int slo = __builtin_amdgcn_update_dpp(0, lo, CTRL, RMASK, 0xf, false);
    const int shi = __builtin_amdgcn_update_dpp(0x7FF00000, hi, CTRL, RMASK, 0xf, false);
    return fmin(v, __hiloint2double(shi, slo));
}
__device__ __forceinline__ double wmind64(double v) {
    v = dmin_step<0x111, 0xf>(v);
    v = dmin_step<0x112, 0xf>(v);
    v = dmin_step<0x114, 0xf>(v);
    v = dmin_step<0x118, 0xf>(v);
    v = dmin_step<0x142, 0xa>(v);
    v = dmin_step<0x143, 0xc>(v);
    return v;
}
// payload variant: identity key=+inf (never selected vs finite), payload rides.
template <int CTRL, int RMASK>
__device__ __forceinline__ void dminp_step(double& v, float& p) {
    const int lo = __double2loint(v), hi = __double2hiint(v);
    const int slo = __builtin_amdgcn_update_dpp(0, lo, CTRL, RMASK, 0xf, false);
    const int shi = __builtin_amdgcn_update_dpp(0x7FF00000, hi, CTRL, RMASK, 0xf, false);
    const int spi = __builtin_amdgcn_update_dpp(0, __float_as_int(p), CTRL, RMASK, 0xf, false);
    const double sv = __hiloint2double(shi, slo);
    if (sv < v) { v = sv; p = __int_as_float(spi); }
}
__device__ __forceinline__ void wminp64(double& v, float& p) {
    dminp_step<0x111, 0xf>(v, p);
    dminp_step<0x112, 0xf>(v, p);
    dminp_step<0x114, 0xf>(v, p);
    dminp_step<0x118, 0xf>(v, p);
    dminp_step<0x142, 0xa>(v, p);   // row_bcast15
    dminp_step<0x143, 0xc>(v, p);   // row_bcast31
}

// ---------------------------------------------------------------------------
// QKV projection: X[S,E] @ W^T + b -> head-major [H][S][D] f32.
// ---------------------------------------------------------------------------
__global__ __launch_bounds__(256) void qkv_gemm(
    const float* __restrict__ X,
    const float* __restrict__ W0, const float* __restrict__ b0,
    const float* __restrict__ W1, const float* __restrict__ b1,
    const float* __restrict__ W2, const float* __restrict__ b2,
    float* __restrict__ Q, float* __restrict__ K, float* __restrict__ V)
{
    const int z = blockIdx.z;
    const float* W    = (z == 0) ? W0 : (z == 1) ? W1 : W2;
    const float* bias = (z == 0) ? b0 : (z == 1) ? b1 : b2;
    float* dst        = (z == 0) ? Q  : (z == 1) ? K  : V;
    const int o0 = blockIdx.x * 128, s0 = blockIdx.y * 128;
    __shared__ float As[16][132];   // [k][m]
    __shared__ float Bs[16][132];   // [k][n]
    const int tid = threadIdx.x;
    const int ty = tid >> 4, tx = tid & 15;
    const int r = tid >> 1, kq = (tid & 1) << 3;
    float acc[8][8] = {};
    for (int kb = 0; kb < E_; kb += 16) {
        float4 a0 = *(const float4*)&X[(size_t)(s0 + r) * E_ + kb + kq];
        float4 a1 = *(const float4*)&X[(size_t)(s0 + r) * E_ + kb + kq + 4];
        float4 w0 = *(const float4*)&W[(size_t)(o0 + r) * E_ + kb + kq];
        float4 w1 = *(const float4*)&W[(size_t)(o0 + r) * E_ + kb + kq + 4];
        __syncthreads();
        As[kq+0][r]=a0.x; As[kq+1][r]=a0.y; As[kq+2][r]=a0.z; As[kq+3][r]=a0.w;
        As[kq+4][r]=a1.x; As[kq+5][r]=a1.y; As[kq+6][r]=a1.z; As[kq+7][r]=a1.w;
        Bs[kq+0][r]=w0.x; Bs[kq+1][r]=w0.y; Bs[kq+2][r]=w0.z; Bs[kq+3][r]=w0.w;
        Bs[kq+4][r]=w1.x; Bs[kq+5][r]=w1.y; Bs[kq+6][r]=w1.z; Bs[kq+7][r]=w1.w;
        __syncthreads();
        #pragma unroll
        for (int kk = 0; kk < 16; ++kk) {
            float av[8], bv[8];
            *(float4*)&av[0] = *(const float4*)&As[kk][ty * 8];
            *(float4*)&av[4] = *(const float4*)&As[kk][ty * 8 + 4];
            *(float4*)&bv[0] = *(const float4*)&Bs[kk][tx * 8];
            *(float4*)&bv[4] = *(const float4*)&Bs[kk][tx * 8 + 4];
            #pragma unroll
            for (int i = 0; i < 8; ++i)
                #pragma unroll
                for (int j = 0; j < 8; ++j) acc[i][j] += av[i] * bv[j];
        }
    }
    #pragma unroll
    for (int i = 0; i < 8; ++i) {
        const int s = s0 + ty * 8 + i;
        #pragma unroll
        for (int jq = 0; jq < 2; ++jq) {
            const int o = o0 + tx * 8 + jq * 4;
            float4 v;
            v.x = acc[i][jq*4+0] + bias[o+0];
            v.y = acc[i][jq*4+1] + bias[o+1];
            v.z = acc[i][jq*4+2] + bias[o+2];
            v.w = acc[i][jq*4+3] + bias[o+3];
            if (z == 0) { v.x *= 0.125f; v.y *= 0.125f; v.z *= 0.125f; v.w *= 0.125f; }
            *(float4*)&dst[((size_t)(o >> 6) * S_ + s) * D_ + (o & 63)] = v;
        }
    }
}

// ---------------------------------------------------------------------------
// Output projection: Y[S,E] = X[S,E] @ Wo^T + bo
// ---------------------------------------------------------------------------
__global__ __launch_bounds__(256) void proj_gemm(
    const float* __restrict__ X, const float* __restrict__ W,
    const float* __restrict__ bias, float* __restrict__ Y)
{
    const int o0 = blockIdx.x * 128, s0 = blockIdx.y * 128;
    __shared__ float As[16][132];
    __shared__ float Bs[16][132];
    const int tid = threadIdx.x;
    const int ty = tid >> 4, tx = tid & 15;
    const int r = tid >> 1, kq = (tid & 1) << 3;
    float acc[8][8] = {};
    for (int kb = 0; kb < E_; kb += 16) {
        float4 a0 = *(const float4*)&X[(size_t)(s0 + r) * E_ + kb + kq];
        float4 a1 = *(const float4*)&X[(size_t)(s0 + r) * E_ + kb + kq + 4];
        float4 w0 = *(const float4*)&W[(size_t)(o0 + r) * E_ + kb + kq];
        float4 w1 = *(const float4*)&W[(size_t)(o0 + r) * E_ + kb + kq + 4];
        __syncthreads();
        As[kq+0][r]=a0.x; As[kq+1][r]=a0.y; As[kq+2][r]=a0.z; As[kq+3][r]=a0.w;
        As[kq+4][r]=a1.x; As[kq+5][r]=a1.y; As[kq+6][r]=a1.z; As[kq+7][r]=a1.w;
        Bs[kq+0][r]=w0.x; Bs[kq+1][r]=w0.y; Bs[kq+2][r]=w0.z; Bs[kq+3][r]=w0.w;
        Bs[kq+4][r]=w1.x; Bs[kq+5][r]=w1.y; Bs[kq+6][r]=w1.z; Bs[kq+7][r]=w1.w;
        __syncthreads();
        #pragma unroll
        for (int kk = 0; kk < 16; ++kk) {
            float av[8], bv[8];
            *(float4*)&av[0] = *(const float4*)&As[kk][ty * 8];
            *(float4*)&av[4] = *(const float4*)&As[kk][ty * 8 + 4];
            *(float4*)&bv[0] = *(const float4*)&Bs[kk][tx * 8];
            *(float4*)&bv[4] = *(const float4*)&Bs[kk][tx * 8 + 4];
            #pragma unroll
            for (int i = 0; i < 8; ++i)
                #pragma unroll
                for (int j = 0; j < 8; ++j) acc[i][j] += av[i] * bv[j];
        }
    }
    #pragma unroll
    for (int i = 0; i < 8; ++i) {
        const int s = s0 + ty * 8 + i;
        #pragma unroll
        for (int jq = 0; jq < 2; ++jq) {
            const int o = o0 + tx * 8 + jq * 4;
            float4 v;
            v.x = acc[i][jq*4+0] + bias[o+0];
            v.y = acc[i][jq*4+1] + bias[o+1];
            v.z = acc[i][jq*4+2] + bias[o+2];
            v.w = acc[i][jq*4+3] + bias[o+3];
            *(float4*)&Y[(size_t)s * E_ + o] = v;
        }
    }
}

// ---------------------------------------------------------------------------
// Sc[h][i][j] = Q[h][i] . K[h][j] (bf16). Lower-tri tiles only. k-major LDS.
// ---------------------------------------------------------------------------
__global__ __launch_bounds__(256) void sc_gemm(const float* __restrict__ Q,
                                               const float* __restrict__ K,
                                               u16* __restrict__ Sc)
{
    const int h = blockIdx.z;
    const int jt = blockIdx.x, it = blockIdx.y;
    if (jt > it) return;
    const int i0 = it * 64, j0 = jt * 64;
    __shared__ float Qs[64][65];   // [k][m]
    __shared__ float Ks[64][65];   // [k][n]
    const float* Qh = Q + (size_t)h * S_ * D_;
    const float* Kh = K + (size_t)h * S_ * D_;
    const int tid = threadIdx.x;
    for (int idx = tid; idx < 1024; idx += 256) {
        const int rr = idx >> 4, c4 = (idx & 15) << 2;
        float4 q4 = *(const float4*)&Qh[(size_t)(i0 + rr) * D_ + c4];
        Qs[c4 + 0][rr] = q4.x; Qs[c4 + 1][rr] = q4.y; Qs[c4 + 2][rr] = q4.z; Qs[c4 + 3][rr] = q4.w;
        float4 k4 = *(const float4*)&Kh[(size_t)(j0 + rr) * D_ + c4];
        Ks[c4 + 0][rr] = k4.x; Ks[c4 + 1][rr] = k4.y; Ks[c4 + 2][rr] = k4.z; Ks[c4 + 3][rr] = k4.w;
    }
    __syncthreads();
    const int ty = tid >> 4, tx = tid & 15;
    float acc[4][4] = {};
    #pragma unroll 4
    for (int kk = 0; kk < 64; ++kk) {
        float4 a4 = *(const float4*)&Qs[kk][ty * 4];
        float4 b4 = *(const float4*)&Ks[kk][tx * 4];
        const float av[4] = {a4.x, a4.y, a4.z, a4.w};
        const float bv[4] = {b4.x, b4.y, b4.z, b4.w};
        #pragma unroll
        for (int i = 0; i < 4; ++i)
            #pragma unroll
            for (int j = 0; j < 4; ++j) acc[i][j] += av[i] * bv[j];
    }
    u16* out = Sc + ((size_t)h * S_ + i0) * S_ + j0;
    #pragma unroll
    for (int i = 0; i < 4; ++i)
        #pragma unroll
        for (int j = 0; j < 4; ++j)
            out[(size_t)(ty * 4 + i) * S_ + tx * 4 + j] = f2bf(acc[i][j]);
}

// ---------------------------------------------------------------------------
// prep_kernel: rsum per scan row + acc-init over rows 0..407 (global atomics).
// ---------------------------------------------------------------------------
__global__ __launch_bounds__(256) void prep_kernel(const u16* __restrict__ Sc,
                                                   float* __restrict__ rsumG,
                                                   float* __restrict__ accG)
{
    const int h = blockIdx.y;
    const int wave = threadIdx.x >> 6, lane = threadIdx.x & 63;
    const int bx = blockIdx.x;
    if (bx < NSCAN_ / 4) {
        const int tok = CB_ + bx * 4 + wave;
        const u16* row = Sc + ((size_t)h * S_ + tok) * S_ + (tok - RB_);
        float sm = 0.f;
        #pragma unroll
        for (int k = 0; k < 4; ++k) {
            const int j = k * 64 + lane;
            if (j <= RB_) sm += __expf(bf2f(row[j]));
        }
        const float z = wsum64(sm);
        if (lane == 0) rsumG[(size_t)h * NSCAN_ + tok - CB_] = z;
    } else {
        const int t = (bx - NSCAN_ / 4) * 4 + wave;   // 0..407
        const u16* row = Sc + ((size_t)h * S_ + t) * S_;
        float sm = 0.f;
        for (int c = lane; c <= t; c += 64) sm += __expf(bf2f(row[c]));
        const float z = wsum64(sm);
        const float w = __powf(PEN_, (float)(CB_ - 1 - t)) / z;
        for (int c = lane; c <= t; c += 64)
            atomicAdd(&accG[h * CB_ + c], __expf(bf2f(row[c])) * w);
    }
}

// ---------------------------------------------------------------------------
// MERGED kernel. R5: SOFTWARE-PIPELINED scan.
// R1/R3/R4 proved the scan iteration cost is the serial dependency chain
// (invariant to barrier count / drain semantics). R5 moves everything that
// does not depend on the eviction OFF the chain:
//  r5a. Speculative gather+exp+wsum for row t+1 during body t, using
//       pre-eviction columns. Only ONE thread's column changes per iter and
//       its new column (li(t)-1) is STATIC, as is the candidate's (li(t+1)-1).
//       Corrections: e fix via uniform ec1 = exp(row_{t+1}[li(t)-1]);
//       S(t+1) = Sspec - esL[ev(t)] + ec1 (esL = published spec e's).
//  r5b. Payload-carrying DPP min: the evicted slot's (corrected) exp rides
//       with the key -> no post-combine gather/exp. (R2's failure is
//       attributed to the fragile vmcnt(6) store-counting, replaced since
//       R3 by the count-robust WAIT_VM(3): >=3 loads are always issued
//       after the staged row's load, independent of stores/spills.)
//  r5c. Remaining serial chain/iter: combine-read -> select -> Z -> invZ ->
//       hacc -> keypack -> wminp64 -> publish -> barrier (~420 cy vs ~1170).
//  Structure: ramp iters 408-412 in the R4-proven form; transition body 413
//  primes pipeline registers; steady bodies 414..2047; epilogue finishes
//  row 2047's hOut. Buffers: 3 row bufs (t,t+1 read; t+2 staged), 4-deep
//  load pipe (regs hold rows t+2..t+5), parity-ping-pong reduction slots.
// ---------------------------------------------------------------------------
#define NFULL_ (CB_ * H_)          /* 6528  full-attn blocks (r<CB)  */
#define NPART_ (NSCAN_ * H_)       /* 26240 recent-partial blocks    */

__global__ __launch_bounds__(256) void scan_fill(const u16* __restrict__ Sc,
                                                 const float* __restrict__ accG,
                                                 const float* __restrict__ rsumG,
                                                 u16* __restrict__ heavyOut,
                                                 const float* __restrict__ V,
                                                 float* __restrict__ O)
{
    __shared__ __align__(16) char ldsPool[22112];
    const int bid = blockIdx.x;
    const int tid = threadIdx.x;

    if (bid >= 16) {
        // ---------------- fill paths: dense attention work ----------------
        float* sbuf  = (float*)ldsPool;            // up to 416 f32
        float* wred  = (float*)(ldsPool + 1664);   // 4 f32
        float* opart = (float*)(ldsPool + 1696);   // 256 f32
        const int lane = tid & 63, wave = tid >> 6;
        int h, r, c0, n;
        bool partial;
        if (bid < 16 + NFULL_) {                   // r < CB: full causal row
            const int t2 = bid - 16;
            r = t2 >> 4; h = t2 & 15;
            c0 = 0; n = r + 1; partial = false;
        } else {                                   // r >= CB: recent window only
            const int idx = bid - 16 - NFULL_;
            r = CB_ + (idx >> 4); h = idx & 15;
            c0 = r - RB_; n = RB_ + 1; partial = true;
        }
        const u16* srow = Sc + ((size_t)h * S_ + r) * S_;
        float ls = 0.f;
        for (int i = tid; i < n; i += 256) {
            const float p = __expf(bf2f(srow[c0 + i]));
            sbuf[i] = p; ls += p;
        }
        ls = wsum64(ls);
        if (lane == 0) wred[wave] = ls;
        __syncthreads();
        const float Z = wred[0] + wred[1] + wred[2] + wred[3];
        float pv = 0.f;
        const float* vh = V + (size_t)h * S_ * D_;
        for (int i = wave; i < n; i += 4)
            pv += sbuf[i] * vh[(size_t)(c0 + i) * D_ + lane];
        opart[wave * 64 + lane] = pv;
        __syncthreads();
        if (tid < 64) {
            const float tot = opart[tid] + opart[64 + tid] + opart[128 + tid] + opart[192 + tid];
            O[(size_t)r * E_ + h * D_ + tid] = partial ? tot : (tot / Z);
        }
        return;
    }

    // ---------------- scan path: 4 waves, one slot per thread ----------------
    __builtin_amdgcn_s_setprio(3);
    const int h = bid;
    const int lane = tid & 63, wv = tid >> 6;
    float*  ring    = (float*)ldsPool;             // 256 f32
    float*  rsumLDS = (float*)(ldsPool + 1024);    // NSCAN f32
    u16*    buf_0   = (u16*)(ldsPool + 7584);      // 4096 B
    u16*    buf_1   = (u16*)(ldsPool + 11680);     // 4096 B
    u16*    buf_2   = (u16*)(ldsPool + 15776);     // 4096 B
    float*  esL     = (float*)(ldsPool + 19872);   // 2 x 256 f32 (parity)
    double* kredL   = (double*)(ldsPool + 21920);  // 2 x 4 f64
    float*  payL    = (float*)(ldsPool + 21984);   // 2 x 4 f32
    float*  SspecL  = (float*)(ldsPool + 22016);   // 2 x 4 f32
    float*  wredL   = (float*)(ldsPool + 22048);   // 2 x 4 f32 (ramp)
    float*  el1L    = (float*)(ldsPool + 22080);   // 2 f32 (ramp)
    float*  sredL   = (float*)(ldsPool + 22088);   // 4 f32 (transition)
    const u16* sch = Sc + (size_t)h * S_ * S_;
    const float* accH = accG + h * CB_;
    u16* hOutH = heavyOut + (size_t)h * NSCAN_ * HB_;

    const bool vHeavy = (tid < HB_);
    const bool vRing  = (tid <= RB_);
    const bool vCand  = (tid == 255);

    u32x4 p0, p1, p2, p3;
    #define ISSUE1(BUF, ROWI)                                                 \
        do {                                                                  \
            const void* _ap = (const void*)((const char*)(sch + (size_t)(ROWI) * S_) + tid * 16); \
            asm volatile("global_load_dwordx4 %0, %1, off"                    \
                         : "=&v"(BUF) : "v"(_ap) : "memory");                 \
        } while (0)
    #define WAIT_VM(N) asm volatile("s_waitcnt vmcnt(" #N ")" ::: "memory")
    #define SBAR() asm volatile("s_waitcnt lgkmcnt(0)\n\ts_barrier" ::: "memory")

    ISSUE1(p0, CB_ + 0);   // 408
    ISSUE1(p1, CB_ + 1);   // 409
    ISSUE1(p2, CB_ + 2);   // 410
    ISSUE1(p3, CB_ + 3);   // 411

    for (int i = tid; i < NSCAN_; i += 256) rsumLDS[i] = rsumG[(size_t)h * NSCAN_ + i];
    for (int c = HB_ + tid; c < CB_; c += 256) ring[c & 255] = accH[c];
    int   hcol = vHeavy ? tid : 0;
    float hacc = vHeavy ? accH[tid] : POSINF;
    float accc;
    // pipeline registers
    float e_prev, es_spec, el1_prev, ew0_prev, ec1_cur, ec255_cur, ew0_cur;
    float expw_prev, S_prev, rsum_prev;

    __syncthreads();                 // init visible; drains p0..p3
    ((u32x4*)buf_0)[tid] = p0;       // row 408
    ((u32x4*)buf_1)[tid] = p1;       // row 409
    ISSUE1(p0, CB_ + 4);             // 412
    ISSUE1(p1, CB_ + 5);             // 413
    __syncthreads();                 // buf0/1 visible (drains p0/p1 too)

    {   // peeled tok = 408 (li = 204): no eviction (R4-proven form)
        ((u32x4*)buf_2)[tid] = p2;   // row 410 (drained above)
        ISSUE1(p2, CB_ + 6);         // 414
        const u16* srow = buf_0;
        const float sg = bf2f(srow[hcol]);
        const float e  = vHeavy ? __expf(sg) : 0.f;
        const float ls = wsum64_63(e);
        if (lane == 63) wredL[wv] = ls;
        float oldw = 0.f, expw = 0.f;
        if (vRing) {
            expw = __expf(bf2f(srow[HB_ + tid]));
            oldw = (tid == RB_) ? 0.f : ring[(HB_ + tid) & 255];
        }
        __syncthreads();
        const float4 ws = *(const float4*)wredL;
        const float Z = ws.x + ws.y + ws.z + ws.w + rsumLDS[0];
        const float invZ = __fdividef(1.f, Z);
        hacc = hacc * PEN_ + e * invZ;
        if (vHeavy) hOutH[tid] = (u16)tid;
        if (vRing)  ring[(HB_ + tid) & 255] = oldw * PEN_ + expw * invZ;
        __syncthreads();
        accc = ring[HB_ & 255];
    }

    // ---- ramp iters (R4-proven one-barrier-pair form, full __syncthreads) ----
    #define RAMP_ITER(TOK, RG, SB, DB, P)                                        \
    do {                                                                         \
        const int _si_tok = (TOK);                                               \
        const int _si_li  = _si_tok - RB_;                                       \
        ((u32x4*)buf_##DB)[tid] = RG;       /* stage row TOK+2 (drained) */      \
        ISSUE1(RG, _si_tok + 6);                                                 \
        const u16* _si_srow = buf_##SB;                                          \
        const int   _si_hc = vCand ? (_si_li - 1) : hcol;                        \
        const float _si_ha = vCand ? accc : hacc;                                \
        const float _si_sg = bf2f(_si_srow[_si_hc]);                             \
        float _si_expw = 0.f;                                                    \
        if (vRing) _si_expw = __expf(bf2f(_si_srow[_si_li + tid]));              \
        const float _si_e = (vHeavy || vCand) ? __expf(_si_sg) : 0.f;            \
        const float _si_ls = wsum64_63(_si_e);                                   \
        double _si_key = __hiloint2double(__float_as_int(_si_ha),                \
                                          ((2047 - _si_hc) << 8) | tid);         \
        _si_key = wmind64(_si_key);                                              \
        if (lane == 63) {                                                        \
            wredL[(P)*4+wv] = _si_ls;                                            \
            kredL[(P)*4+wv] = _si_key;                                           \
            if (wv == 3) el1L[P] = _si_e;                                        \
        }                                                                        \
        __syncthreads();                                                         \
        const float4 _si_ws = *(const float4*)&wredL[(P)*4];                     \
        const double _si_km = fmin(fmin(kredL[(P)*4+0], kredL[(P)*4+1]),         \
                                   fmin(kredL[(P)*4+2], kredL[(P)*4+3]));        \
        const int _si_lo  = __double2loint(_si_km);                              \
        const int _si_ev  = _si_lo & 255;                                        \
        const int _si_hev = 2047 - (_si_lo >> 8);                                \
        const float _si_ebc = __expf(bf2f(_si_srow[_si_hev]));                   \
        const float _si_el1 = el1L[P];                                           \
        const float _si_rsum = rsumLDS[_si_tok - CB_];                           \
        const float _si_Z = (_si_ws.x + _si_ws.y + _si_ws.z + _si_ws.w)          \
                            - _si_ebc + _si_rsum;                                \
        const float _si_invZ = __fdividef(1.f, _si_Z);                           \
        const float _si_oldw0 = ring[_si_li & 255];                              \
        if (vRing && tid != 0) {                                                 \
            const float _si_oldw = (tid == RB_) ? 0.f : ring[(_si_li + tid) & 255]; \
            ring[(_si_li + tid) & 255] = _si_oldw * PEN_ + _si_expw * _si_invZ;  \
        }                                                                        \
        const bool _si_m = (tid == _si_ev);                                      \
        hcol = _si_m ? (_si_li - 1) : _si_hc;                                    \
        hacc = (_si_m ? accc : _si_ha) * PEN_                                    \
             + (_si_m ? _si_el1 : _si_e) * _si_invZ;                             \
        const float _si_ew0 = __expf(bf2f(_si_srow[_si_li]));                    \
        accc = _si_oldw0 * PEN_ + _si_ew0 * _si_invZ;                            \
        if (vHeavy) hOutH[(size_t)(_si_tok - CB_) * HB_ + tid] = (u16)hcol;      \
        __syncthreads();                                                         \
    } while (0)

    RAMP_ITER(CB_ + 1, p3, 1, 0, 1);   // 409: stage 411->buf0, issue 415
    RAMP_ITER(CB_ + 2, p0, 2, 1, 0);   // 410: stage 412->buf1, issue 416
    RAMP_ITER(CB_ + 3, p1, 0, 2, 1);   // 411: stage 413->buf2, issue 417
    RAMP_ITER(CB_ + 4, p2, 1, 0, 0);   // 412: stage 414->buf0, issue 418
    #undef RAMP_ITER

    {   // ---- transition: iter 413 phase-A + pipeline priming ----
        const int t = CB_ + 5;            // 413
        const int liC = t - RB_;          // 209
        const u16* rowT = buf_2;          // row 413
        const u16* rowN = buf_0;          // row 414
        ((u32x4*)buf_1)[tid] = p3;        // stage row 415 (drained)
        ISSUE1(p3, t + 6);                // 419
        float eC;
        if (vHeavy)      eC = __expf(bf2f(rowT[hcol]));
        else if (vCand)  eC = __expf(bf2f(rowT[liC - 1]));
        else             eC = 0.f;
        const int   hc = vCand ? (liC - 1) : hcol;
        const float ha = vCand ? accc : hacc;
        double key = __hiloint2double(__float_as_int(ha), ((2047 - hc) << 8) | tid);
        float pay = eC;
        wminp64(key, pay);
        if (lane == 63) { kredL[4 + wv] = key; payL[4 + wv] = pay; }   // P=1
        const float ls = wsum64_63(eC);
        if (lane == 63) sredL[wv] = ls;
        // spec row 414:
        const float ec1N   = __expf(bf2f(rowN[liC - 1]));
        const float ec255N = __expf(bf2f(rowN[liC]));
        const float ew0N   = __expf(bf2f(rowN[liC + 1]));
        float esN;
        if (vHeavy)      esN = __expf(bf2f(rowN[hcol]));
        else if (vCand)  esN = ec255N;
        else             esN = 0.f;
        esL[256 + tid] = esN;                                           // P=1
        const float ls2 = wsum64_63(esN);
        if (lane == 63) SspecL[4 + wv] = ls2;                           // P=1
        el1_prev  = __expf(bf2f(rowT[liC - 1]));
        ew0_prev  = __expf(bf2f(rowT[liC]));
        expw_prev = vRing ? __expf(bf2f(rowT[liC + tid])) : 0.f;
        e_prev = eC; es_spec = esN;
        ec1_cur = ec1N; ec255_cur = ec255N; ew0_cur = ew0N;
        rsum_prev = rsumLDS[t - CB_];
        __syncthreads();
        S_prev = sredL[0] + sredL[1] + sredL[2] + sredL[3];
    }

    // ---- steady body: finishes iter t-1, reduces min(t), specs row t+1 ----
    #define SBODY(TOK, RG, SB0, SB1, DB, P)                                      \
    do {                                                                         \
        const int _t   = (TOK);                                                  \
        const int _liP = _t - RB_ - 1;                                           \
        const int _liC = _t - RB_;                                               \
        WAIT_VM(3);                                                              \
        ((u32x4*)buf_##DB)[tid] = RG;                                            \
        ISSUE1(RG, (_t + 6 < S_) ? _t + 6 : S_ - 1);                             \
        const u16* _rowT = buf_##SB0;                                            \
        const u16* _rowN = buf_##SB1;                                            \
        double _k0 = kredL[(1-(P))*4+0], _k1 = kredL[(1-(P))*4+1];               \
        double _k2 = kredL[(1-(P))*4+2], _k3 = kredL[(1-(P))*4+3];               \
        float _q0 = payL[(1-(P))*4+0], _q1 = payL[(1-(P))*4+1];                  \
        float _q2 = payL[(1-(P))*4+2], _q3 = payL[(1-(P))*4+3];                  \
        const float4 _w4 = *(const float4*)&SspecL[(1-(P))*4];                   \
        float _oldw = 0.f;                                                       \
        if (vRing) _oldw = (tid == RB_) ? 0.f : ring[(_liP + tid) & 255];        \
        const float _oldw0 = ring[_liP & 255];                                   \
        const float _rs = rsumLDS[_t - CB_];                                     \
        double _km = _k0; float _pm = _q0;                                       \
        if (_k1 < _km) { _km = _k1; _pm = _q1; }                                 \
        if (_k2 < _km) { _km = _k2; _pm = _q2; }                                 \
        if (_k3 < _km) { _km = _k3; _pm = _q3; }                                 \
        const int _ev = __double2loint(_km) & 255;                               \
        const float _Z = S_prev - _pm + rsum_prev;                               \
        const float _invZ = __fdividef(1.f, _Z);                                 \
        const bool _m = (tid == _ev);                                            \
        hacc = (_m ? accc : hacc) * PEN_ + (_m ? el1_prev : e_prev) * _invZ;     \
        if (_m && _ev != 255) hcol = _liP - 1;                                   \
        const float _acccN = _oldw0 * PEN_ + ew0_prev * _invZ;                   \
        if (vRing && tid != 0)                                                   \
            ring[(_liP + tid) & 255] = _oldw * PEN_ + expw_prev * _invZ;         \
        if (vHeavy) hOutH[(size_t)(_t - 1 - CB_) * HB_ + tid] = (u16)hcol;       \
        accc = _acccN;                                                           \
        const float _eC = (_m && _ev != 255) ? ec1_cur : es_spec;                \
        float _sc = 0.f;                                                         \
        if (_ev != 255) _sc = ec1_cur - esL[(1-(P))*256 + _ev];                  \
        const float _S = _w4.x + _w4.y + _w4.z + _w4.w + _sc;                    \
        const int   _hc = vCand ? (_liC - 1) : hcol;                             \
        const float _ha = vCand ? accc : hacc;                                   \
        double _key = __hiloint2double(__float_as_int(_ha),                      \
                                       ((2047 - _hc) << 8) | tid);               \
        float _pay = _eC;                                                        \
        wminp64(_key, _pay);                                                     \
        if (lane == 63) { kredL[(P)*4+wv] = _key; payL[(P)*4+wv] = _pay; }       \
        const float _ec1N   = __expf(bf2f(_rowN[_liC - 1]));                     \
        const float _ec255N = __expf(bf2f(_rowN[_liC]));                         \
        const float _ew0N   = __expf(bf2f(_rowN[_liC + 1]));                     \
        float _esN;                                                              \
        if (vHeavy)      _esN = __expf(bf2f(_rowN[hcol]));                       \
        else if (vCand)  _esN = _ec255N;                                         \
        else             _esN = 0.f;                                             \
        esL[(P)*256 + tid] = _esN;                                               \
        const float _ls = wsum64_63(_esN);                                       \
        if (lane == 63) SspecL[(P)*4+wv] = _ls;                                  \
        const float _expwC = vRing ? __expf(bf2f(_rowT[_liC + tid])) : 0.f;      \
        e_prev = _eC; es_spec = _esN;                                            \
        el1_prev = ec255_cur; ew0_prev = ew0_cur;                                \
        ec1_cur = _ec1N; ec255_cur = _ec255N; ew0_cur = _ew0N;                   \
        expw_prev = _expwC; S_prev = _S; rsum_prev = _rs;                        \
        SBAR();                                                                  \
    } while (0)

    for (int t0 = CB_ + 6; t0 + 11 <= S_ - 3; t0 += 12) {   // 414 .. 2045
        SBODY(t0 + 0,  p0, 0, 1, 2, 0);
        SBODY(t0 + 1,  p1, 1, 2, 0, 1);
        SBODY(t0 + 2,  p2, 2, 0, 1, 0);
        SBODY(t0 + 3,  p3, 0, 1, 2, 1);
        SBODY(t0 + 4,  p0, 1, 2, 0, 0);
        SBODY(t0 + 5,  p1, 2, 0, 1, 1);
        SBODY(t0 + 6,  p2, 0, 1, 2, 0);
        SBODY(t0 + 7,  p3, 1, 2, 0, 1);
        SBODY(t0 + 8,  p0, 2, 0, 1, 0);
        SBODY(t0 + 9,  p1, 0, 1, 2, 1);
        SBODY(t0 + 10, p2, 1, 2, 0, 0);
        SBODY(t0 + 11, p3, 2, 0, 1, 1);
    }
    SBODY(S_ - 2, p0, 0, 1, 2, 0);   // 2046
    SBODY(S_ - 1, p1, 1, 2, 0, 1);   // 2047
    #undef SBODY

    {   // epilogue: finish iter 2047 (hOut only)
        double k0 = kredL[4], k1 = kredL[5], k2 = kredL[6], k3 = kredL[7]; // P(2047)=1
        double km = k0;
        if (k1 < km) km = k1;
        if (k2 < km) km = k2;
        if (k3 < km) km = k3;
        const int ev = __double2loint(km) & 255;
        if (tid == ev && ev != 255) hcol = (S_ - 1 - RB_) - 1;
        if (vHeavy) hOutH[(size_t)(S_ - 1 - CB_) * HB_ + tid] = (u16)hcol;
    }
    #undef ISSUE1
    #undef WAIT_VM
    #undef SBAR
}

// ---------------------------------------------------------------------------
// heavy_merge: rows r>=CB. Gather 204 heavy cols, add to the recent-window
// partial already in O, normalize by (heavy sum + rsumG).
// ---------------------------------------------------------------------------
__global__ __launch_bounds__(256) void heavy_merge(const u16* __restrict__ Sc,
                                                   const float* __restrict__ V,
                                                   const u16* __restrict__ heavyIn,
                                                   const float* __restrict__ rsumG,
                                                   float* __restrict__ O)
{
    const int idx = blockIdx.x;
    const int r = CB_ + (idx >> 4), h = idx & 15;
    const int tid = threadIdx.x;
    const int lane = tid & 63, wave = tid >> 6;
    __shared__ float sbuf[208];
    __shared__ u16 cbuf[208];
    __shared__ float wred[4];
    __shared__ float opart[4][64];
    const u16* srow = Sc + ((size_t)h * S_ + r) * S_;
    const u16* hrow = heavyIn + ((size_t)h * NSCAN_ + (r - CB_)) * HB_;
    float ls = 0.f;
    for (int i = tid; i < HB_; i += 256) {
        const int col = hrow[i];
        const float p = __expf(bf2f(srow[col]));
        sbuf[i] = p; cbuf[i] = (u16)col;
        ls += p;
    }
    ls = wsum64(ls);
    if (lane == 0) wred[wave] = ls;
    __syncthreads();
    const float Z = wred[0] + wred[1] + wred[2] + wred[3]
                  + rsumG[(size_t)h * NSCAN_ + r - CB_];
    float pv = 0.f;
    const float* vh = V + (size_t)h * S_ * D_;
    for (int i = wave; i < HB_; i += 4)
        pv += sbuf[i] * vh[(size_t)cbuf[i] * D_ + lane];
    opart[wave][lane] = pv;
    __syncthreads();
    if (tid < 64) {
        const float tot = opart[0][tid] + opart[1][tid] + opart[2][tid] + opart[3][tid];
        float* op = &O[(size_t)r * E_ + h * D_ + tid];
        *op = (*op + tot) / Z;
    }
}

// ---------------------------------------------------------------------------
extern "C" void kernel_launch(void* const* d_in, const int* in_sizes, int n_in,
                              void* d_out, int out_size, void* d_ws, size_t ws_size,
                              hipStream_t stream)
{
    const float* hs = (const float*)d_in[0];
    const float* Wq = (const float*)d_in[2];
    const float* bq = (const float*)d_in[3];
    const float* Wk = (const float*)d_in[4];
    const float* bk = (const float*)d_in[5];
    const float* Wv = (const float*)d_in[6];
    const float* bv = (const float*)d_in[7];
    const float* Wo = (const float*)d_in[8];
    const float* bo = (const float*)d_in[9];

    char* ws = (char*)d_ws;
    const size_t MB = 1024 * 1024;
    float* Q     = (float*)(ws);                   //   8 MB [H][S][D]
    float* K     = (float*)(ws + 8 * MB);          //   8 MB
    float* V     = (float*)(ws + 16 * MB);         //   8 MB
    u16*   Sc    = (u16*)  (ws + 24 * MB);         // 128 MB [H][S][S] bf16
    u16*   hvy   = (u16*)  (ws + 152 * MB);        // ~10.2 MB [H][NSCAN][HB]
    float* rsumG = (float*)(ws + 163 * MB);        // 105 KB [H][NSCAN]
    float* accG  = (float*)(ws + 164 * MB);        //  26 KB [H][CB]
    float* O     = (float*)(ws + 168 * MB);        //   8 MB [S][E]
    (void)ws_size; (void)in_sizes; (void)n_in; (void)out_size;

    (void)hipMemsetAsync(accG, 0, (size_t)H_ * CB_ * sizeof(float), stream);
    qkv_gemm<<<dim3(8, 16, 3), 256, 0, stream>>>(hs, Wq, bq, Wk, bk, Wv, bv, Q, K, V);
    sc_gemm <<<dim3(32, 32, 16), 256, 0, stream>>>(Q, K, Sc);
    prep_kernel<<<dim3(NSCAN_ / 4 + CB_ / 4, H_), 256, 0, stream>>>(Sc, rsumG, accG);
    scan_fill<<<16 + NFULL_ + NPART_, 256, 0, stream>>>(Sc, accG, rsumG, hvy, V, O);
    heavy_merge<<<NPART_, 256, 0, stream>>>(Sc, V, hvy, rsumG, O);
    proj_gemm<<<dim3(8, 16, 1), 256, 0, stream>>>(O, Wo, bo, (float*)d_out);
}

// Round 7
// 1789.851 us; speedup vs baseline: 1.0755x; 1.0755x over previous
//
#include <hip/hip_runtime.h>

#define S_ 2048
#define E_ 1024
#define H_ 16
#define D_ 64
#define HB_ 204
#define RB_ 204
#define CB_ 408
#define NSCAN_ (S_ - CB_)
#define PEN_ 0.99f
#define NEGINF (-__builtin_huge_valf())
#define POSINF (__builtin_huge_valf())

typedef unsigned short u16;
typedef unsigned int u32;
typedef unsigned int u32x4 __attribute__((ext_vector_type(4)));

__device__ __forceinline__ float bf2f(u16 u) {
    union { u32 u; float f; } a; a.u = ((u32)u) << 16; return a.f;
}
__device__ __forceinline__ u16 f2bf(float f) {
    union { float f; u32 u; } a; a.f = f;
    u32 r = (a.u + 0x7FFFu + ((a.u >> 16) & 1u)) >> 16;
    return (u16)r;
}

// ---------------------------------------------------------------------------
// Wave64 reductions via DPP.
// wsum64: total broadcast (readlane 63 inside).
// wmind64: f64 min valid in lane 63 (keys positive/finite; identity +inf).
// ---------------------------------------------------------------------------
#define DPPF(ID, V, CTRL, RMASK) \
    __int_as_float(__builtin_amdgcn_update_dpp(__float_as_int(ID), __float_as_int(V), CTRL, RMASK, 0xf, false))

__device__ __forceinline__ float wsum64_63(float v) {
    float t;
    t = DPPF(0.f, v, 0x111, 0xf); v += t;
    t = DPPF(0.f, v, 0x112, 0xf); v += t;
    t = DPPF(0.f, v, 0x114, 0xf); v += t;
    t = DPPF(0.f, v, 0x118, 0xf); v += t;
    t = DPPF(0.f, v, 0x142, 0xa); v += t;
    t = DPPF(0.f, v, 0x143, 0xc); v += t;
    return v;                        // lane 63 holds the wave total
}
__device__ __forceinline__ float wsum64(float v) {
    v = wsum64_63(v);
    return __int_as_float(__builtin_amdgcn_readlane(__float_as_int(v), 63));
}
template <int CTRL, int RMASK>
__device__ __forceinline__ double dmin_step(double v) {
    const int lo = __double2loint(v), hi = __double2hiint(v);
    const int slo = __builtin_amdgcn_update_dpp(0, lo, CTRL, RMASK, 0xf, false);
    const int shi = __builtin_amdgcn_update_dpp(0x7FF00000, hi, CTRL, RMASK, 0xf, false);
    return fmin(v, __hiloint2double(shi, slo));
}
__device__ __forceinline__ double wmind64(double v) {
    v = dmin_step<0x111, 0xf>(v);
    v = dmin_step<0x112, 0xf>(v);
    v = dmin_step<0x114, 0xf>(v);
    v = dmin_step<0x118, 0xf>(v);
    v = dmin_step<0x142, 0xa>(v);   // row_bcast15
    v = dmin_step<0x143, 0xc>(v);   // row_bcast31
    return v;                        // lane 63 holds the wave min
}

// ---------------------------------------------------------------------------
// QKV projection: X[S,E] @ W^T + b -> head-major [H][S][D] f32.
// ---------------------------------------------------------------------------
__global__ __launch_bounds__(256) void qkv_gemm(
    const float* __restrict__ X,
    const float* __restrict__ W0, const float* __restrict__ b0,
    const float* __restrict__ W1, const float* __restrict__ b1,
    const float* __restrict__ W2, const float* __restrict__ b2,
    float* __restrict__ Q, float* __restrict__ K, float* __restrict__ V)
{
    const int z = blockIdx.z;
    const float* W    = (z == 0) ? W0 : (z == 1) ? W1 : W2;
    const float* bias = (z == 0) ? b0 : (z == 1) ? b1 : b2;
    float* dst        = (z == 0) ? Q  : (z == 1) ? K  : V;
    const int o0 = blockIdx.x * 128, s0 = blockIdx.y * 128;
    __shared__ float As[16][132];   // [k][m]
    __shared__ float Bs[16][132];   // [k][n]
    const int tid = threadIdx.x;
    const int ty = tid >> 4, tx = tid & 15;
    const int r = tid >> 1, kq = (tid & 1) << 3;
    float acc[8][8] = {};
    for (int kb = 0; kb < E_; kb += 16) {
        float4 a0 = *(const float4*)&X[(size_t)(s0 + r) * E_ + kb + kq];
        float4 a1 = *(const float4*)&X[(size_t)(s0 + r) * E_ + kb + kq + 4];
        float4 w0 = *(const float4*)&W[(size_t)(o0 + r) * E_ + kb + kq];
        float4 w1 = *(const float4*)&W[(size_t)(o0 + r) * E_ + kb + kq + 4];
        __syncthreads();
        As[kq+0][r]=a0.x; As[kq+1][r]=a0.y; As[kq+2][r]=a0.z; As[kq+3][r]=a0.w;
        As[kq+4][r]=a1.x; As[kq+5][r]=a1.y; As[kq+6][r]=a1.z; As[kq+7][r]=a1.w;
        Bs[kq+0][r]=w0.x; Bs[kq+1][r]=w0.y; Bs[kq+2][r]=w0.z; Bs[kq+3][r]=w0.w;
        Bs[kq+4][r]=w1.x; Bs[kq+5][r]=w1.y; Bs[kq+6][r]=w1.z; Bs[kq+7][r]=w1.w;
        __syncthreads();
        #pragma unroll
        for (int kk = 0; kk < 16; ++kk) {
            float av[8], bv[8];
            *(float4*)&av[0] = *(const float4*)&As[kk][ty * 8];
            *(float4*)&av[4] = *(const float4*)&As[kk][ty * 8 + 4];
            *(float4*)&bv[0] = *(const float4*)&Bs[kk][tx * 8];
            *(float4*)&bv[4] = *(const float4*)&Bs[kk][tx * 8 + 4];
            #pragma unroll
            for (int i = 0; i < 8; ++i)
                #pragma unroll
                for (int j = 0; j < 8; ++j) acc[i][j] += av[i] * bv[j];
        }
    }
    #pragma unroll
    for (int i = 0; i < 8; ++i) {
        const int s = s0 + ty * 8 + i;
        #pragma unroll
        for (int jq = 0; jq < 2; ++jq) {
            const int o = o0 + tx * 8 + jq * 4;
            float4 v;
            v.x = acc[i][jq*4+0] + bias[o+0];
            v.y = acc[i][jq*4+1] + bias[o+1];
            v.z = acc[i][jq*4+2] + bias[o+2];
            v.w = acc[i][jq*4+3] + bias[o+3];
            if (z == 0) { v.x *= 0.125f; v.y *= 0.125f; v.z *= 0.125f; v.w *= 0.125f; }
            *(float4*)&dst[((size_t)(o >> 6) * S_ + s) * D_ + (o & 63)] = v;
        }
    }
}

// ---------------------------------------------------------------------------
// Output projection: Y[S,E] = X[S,E] @ Wo^T + bo
// ---------------------------------------------------------------------------
__global__ __launch_bounds__(256) void proj_gemm(
    const float* __restrict__ X, const float* __restrict__ W,
    const float* __restrict__ bias, float* __restrict__ Y)
{
    const int o0 = blockIdx.x * 128, s0 = blockIdx.y * 128;
    __shared__ float As[16][132];
    __shared__ float Bs[16][132];
    const int tid = threadIdx.x;
    const int ty = tid >> 4, tx = tid & 15;
    const int r = tid >> 1, kq = (tid & 1) << 3;
    float acc[8][8] = {};
    for (int kb = 0; kb < E_; kb += 16) {
        float4 a0 = *(const float4*)&X[(size_t)(s0 + r) * E_ + kb + kq];
        float4 a1 = *(const float4*)&X[(size_t)(s0 + r) * E_ + kb + kq + 4];
        float4 w0 = *(const float4*)&W[(size_t)(o0 + r) * E_ + kb + kq];
        float4 w1 = *(const float4*)&W[(size_t)(o0 + r) * E_ + kb + kq + 4];
        __syncthreads();
        As[kq+0][r]=a0.x; As[kq+1][r]=a0.y; As[kq+2][r]=a0.z; As[kq+3][r]=a0.w;
        As[kq+4][r]=a1.x; As[kq+5][r]=a1.y; As[kq+6][r]=a1.z; As[kq+7][r]=a1.w;
        Bs[kq+0][r]=w0.x; Bs[kq+1][r]=w0.y; Bs[kq+2][r]=w0.z; Bs[kq+3][r]=w0.w;
        Bs[kq+4][r]=w1.x; Bs[kq+5][r]=w1.y; Bs[kq+6][r]=w1.z; Bs[kq+7][r]=w1.w;
        __syncthreads();
        #pragma unroll
        for (int kk = 0; kk < 16; ++kk) {
            float av[8], bv[8];
            *(float4*)&av[0] = *(const float4*)&As[kk][ty * 8];
            *(float4*)&av[4] = *(const float4*)&As[kk][ty * 8 + 4];
            *(float4*)&bv[0] = *(const float4*)&Bs[kk][tx * 8];
            *(float4*)&bv[4] = *(const float4*)&Bs[kk][tx * 8 + 4];
            #pragma unroll
            for (int i = 0; i < 8; ++i)
                #pragma unroll
                for (int j = 0; j < 8; ++j) acc[i][j] += av[i] * bv[j];
        }
    }
    #pragma unroll
    for (int i = 0; i < 8; ++i) {
        const int s = s0 + ty * 8 + i;
        #pragma unroll
        for (int jq = 0; jq < 2; ++jq) {
            const int o = o0 + tx * 8 + jq * 4;
            float4 v;
            v.x = acc[i][jq*4+0] + bias[o+0];
            v.y = acc[i][jq*4+1] + bias[o+1];
            v.z = acc[i][jq*4+2] + bias[o+2];
            v.w = acc[i][jq*4+3] + bias[o+3];
            *(float4*)&Y[(size_t)s * E_ + o] = v;
        }
    }
}

// ---------------------------------------------------------------------------
// Sc[h][i][j] = Q[h][i] . K[h][j] (bf16). Lower-tri tiles only. k-major LDS.
// ---------------------------------------------------------------------------
__global__ __launch_bounds__(256) void sc_gemm(const float* __restrict__ Q,
                                               const float* __restrict__ K,
                                               u16* __restrict__ Sc)
{
    const int h = blockIdx.z;
    const int jt = blockIdx.x, it = blockIdx.y;
    if (jt > it) return;
    const int i0 = it * 64, j0 = jt * 64;
    __shared__ float Qs[64][65];   // [k][m]
    __shared__ float Ks[64][65];   // [k][n]
    const float* Qh = Q + (size_t)h * S_ * D_;
    const float* Kh = K + (size_t)h * S_ * D_;
    const int tid = threadIdx.x;
    for (int idx = tid; idx < 1024; idx += 256) {
        const int rr = idx >> 4, c4 = (idx & 15) << 2;
        float4 q4 = *(const float4*)&Qh[(size_t)(i0 + rr) * D_ + c4];
        Qs[c4 + 0][rr] = q4.x; Qs[c4 + 1][rr] = q4.y; Qs[c4 + 2][rr] = q4.z; Qs[c4 + 3][rr] = q4.w;
        float4 k4 = *(const float4*)&Kh[(size_t)(j0 + rr) * D_ + c4];
        Ks[c4 + 0][rr] = k4.x; Ks[c4 + 1][rr] = k4.y; Ks[c4 + 2][rr] = k4.z; Ks[c4 + 3][rr] = k4.w;
    }
    __syncthreads();
    const int ty = tid >> 4, tx = tid & 15;
    float acc[4][4] = {};
    #pragma unroll 4
    for (int kk = 0; kk < 64; ++kk) {
        float4 a4 = *(const float4*)&Qs[kk][ty * 4];
        float4 b4 = *(const float4*)&Ks[kk][tx * 4];
        const float av[4] = {a4.x, a4.y, a4.z, a4.w};
        const float bv[4] = {b4.x, b4.y, b4.z, b4.w};
        #pragma unroll
        for (int i = 0; i < 4; ++i)
            #pragma unroll
            for (int j = 0; j < 4; ++j) acc[i][j] += av[i] * bv[j];
    }
    u16* out = Sc + ((size_t)h * S_ + i0) * S_ + j0;
    #pragma unroll
    for (int i = 0; i < 4; ++i)
        #pragma unroll
        for (int j = 0; j < 4; ++j)
            out[(size_t)(ty * 4 + i) * S_ + tx * 4 + j] = f2bf(acc[i][j]);
}

// ---------------------------------------------------------------------------
// prep_kernel: rsum per scan row + acc-init over rows 0..407 (global atomics).
// ---------------------------------------------------------------------------
__global__ __launch_bounds__(256) void prep_kernel(const u16* __restrict__ Sc,
                                                   float* __restrict__ rsumG,
                                                   float* __restrict__ accG)
{
    const int h = blockIdx.y;
    const int wave = threadIdx.x >> 6, lane = threadIdx.x & 63;
    const int bx = blockIdx.x;
    if (bx < NSCAN_ / 4) {
        const int tok = CB_ + bx * 4 + wave;
        const u16* row = Sc + ((size_t)h * S_ + tok) * S_ + (tok - RB_);
        float sm = 0.f;
        #pragma unroll
        for (int k = 0; k < 4; ++k) {
            const int j = k * 64 + lane;
            if (j <= RB_) sm += __expf(bf2f(row[j]));
        }
        const float z = wsum64(sm);
        if (lane == 0) rsumG[(size_t)h * NSCAN_ + tok - CB_] = z;
    } else {
        const int t = (bx - NSCAN_ / 4) * 4 + wave;   // 0..407
        const u16* row = Sc + ((size_t)h * S_ + t) * S_;
        float sm = 0.f;
        for (int c = lane; c <= t; c += 64) sm += __expf(bf2f(row[c]));
        const float z = wsum64(sm);
        const float w = __powf(PEN_, (float)(CB_ - 1 - t)) / z;
        for (int c = lane; c <= t; c += 64)
            atomicAdd(&accG[h * CB_ + c], __expf(bf2f(row[c])) * w);
    }
}

// ---------------------------------------------------------------------------
// MERGED kernel. R6: ONE-WAVE scan, ZERO barriers, RING IN REGISTERS.
// Evidence: R0(1-wave,2 drains)=1130, R1(4-wave)=904, R3/R4 (wait/barrier
// variants)=926/928, R5(pipelined 4-wave)=1197. Iteration cost is invariant
// to barrier/wait policy -> the floor is the dependent-LDS-trip chain forced
// by cross-wave communication. R6 removes the LDS trips instead:
//  r6a. 1 wave/head, 4 slots/lane (R0 geometry): all reductions are in-wave
//       DPP; the publish->barrier->combine sequence (~300cy of LDS+sync) is
//       gone entirely. Evicted exp via select+readlane (R0-proven).
//  r6b. Ring lives in REGISTERS: cell c -> lane c&63, reg c>>6. Each cell
//       tracks its active column colc (advances +256 when dropped, i.e.
//       when colc==li at iter end after serving as the candidate source;
//       re-initialized by the existing col==tok -> old=0 rule). Ring
//       read/write = register fma; candidate acc = one v_readlane of the
//       cell with colc==li. Kills ~2 dependent LDS trips + handoff.
//  r6c. Keys (hacc/hcol) are known at iter START -> wmind64 issues first
//       and overlaps the gather->exp->wsum chain.
//  r6d. Staging = R0's proven reg pipeline: p0..p3 (4-deep), ISSUE_ROW asm,
//       WAIT_VM(12) (count-robust: rows t+2..t+4 = 12 newer loads always
//       outstanding, independent of store interleave; empirically validated
//       in R0/R1), 2 LDS row buffers, compiler-ordered ds_write->ds_read.
//  Arithmetic identical to R0's slot mapping (same formulas, same 4-slot
//  sum order) -> absmax expected ~R0's 0.012, threshold 0.024.
// ---------------------------------------------------------------------------
#define NFULL_ (CB_ * H_)          /* 6528  full-attn blocks (r<CB)  */
#define NPART_ (NSCAN_ * H_)       /* 26240 recent-partial blocks    */

__global__ __launch_bounds__(256) void scan_fill(const u16* __restrict__ Sc,
                                                 const float* __restrict__ accG,
                                                 const float* __restrict__ rsumG,
                                                 u16* __restrict__ heavyOut,
                                                 const float* __restrict__ V,
                                                 float* __restrict__ O)
{
    __shared__ __align__(16) char ldsPool[14752];
    const int bid = blockIdx.x;
    const int tid = threadIdx.x;

    if (bid >= 16) {
        // ---------------- fill paths: dense attention work ----------------
        float* sbuf  = (float*)ldsPool;            // up to 416 f32
        float* wred  = (float*)(ldsPool + 1664);   // 4 f32
        float* opart = (float*)(ldsPool + 1696);   // 256 f32
        const int lane = tid & 63, wave = tid >> 6;
        int h, r, c0, n;
        bool partial;
        if (bid < 16 + NFULL_) {                   // r < CB: full causal row
            const int t2 = bid - 16;
            r = t2 >> 4; h = t2 & 15;
            c0 = 0; n = r + 1; partial = false;
        } else {                                   // r >= CB: recent window only
            const int idx = bid - 16 - NFULL_;
            r = CB_ + (idx >> 4); h = idx & 15;
            c0 = r - RB_; n = RB_ + 1; partial = true;
        }
        const u16* srow = Sc + ((size_t)h * S_ + r) * S_;
        float ls = 0.f;
        for (int i = tid; i < n; i += 256) {
            const float p = __expf(bf2f(srow[c0 + i]));
            sbuf[i] = p; ls += p;
        }
        ls = wsum64(ls);
        if (lane == 0) wred[wave] = ls;
        __syncthreads();
        const float Z = wred[0] + wred[1] + wred[2] + wred[3];
        float pv = 0.f;
        const float* vh = V + (size_t)h * S_ * D_;
        for (int i = wave; i < n; i += 4)
            pv += sbuf[i] * vh[(size_t)(c0 + i) * D_ + lane];
        opart[wave * 64 + lane] = pv;
        __syncthreads();
        if (tid < 64) {
            const float tot = opart[tid] + opart[64 + tid] + opart[128 + tid] + opart[192 + tid];
            // partial rows: store UNNORMALIZED; heavy_merge adds + divides
            O[(size_t)r * E_ + h * D_ + tid] = partial ? tot : (tot / Z);
        }
        return;
    }

    // ---------------- scan path: ONE wave, 4 slots per lane ----------------
    if (tid >= 64) return;
    __builtin_amdgcn_s_setprio(3);
    const int h = bid;
    const int lane = tid;
    float* rsumLDS = (float*)ldsPool;              // 6560 B
    u16*   rowbufA = (u16*)(ldsPool + 6560);       // 4096 B
    u16*   rowbufB = rowbufA + S_;                 // 4096 B
    const u16* sch = Sc + (size_t)h * S_ * S_;
    const float* accH = accG + h * CB_;
    u16* hOutH = heavyOut + (size_t)h * NSCAN_ * HB_;

    #define ISSUE_ROW(BUF, ROWI)                                                 \
        do {                                                                     \
            const void* _ap = (const void*)((const char*)(sch + (size_t)(ROWI) * S_) + lane * 16); \
            asm volatile("global_load_dwordx4 %0, %4, off\n\t"                   \
                         "global_load_dwordx4 %1, %4, off offset:1024\n\t"       \
                         "global_load_dwordx4 %2, %4, off offset:2048\n\t"       \
                         "global_load_dwordx4 %3, %4, off offset:3072"           \
                         : "=&v"(BUF[0]), "=&v"(BUF[1]), "=&v"(BUF[2]), "=&v"(BUF[3]) \
                         : "v"(_ap) : "memory");                                 \
        } while (0)
    #define WAIT_VM(N) asm volatile("s_waitcnt vmcnt(" #N ")" ::: "memory")

    u32x4 p0[4], p1[4], p2[4], p3[4];
    ISSUE_ROW(p0, CB_ + 0);   // 408
    ISSUE_ROW(p1, CB_ + 1);   // 409
    ISSUE_ROW(p2, CB_ + 2);   // 410
    ISSUE_ROW(p3, CB_ + 3);   // 411

    for (int i = lane; i < NSCAN_; i += 64) rsumLDS[i] = rsumG[(size_t)h * NSCAN_ + i];

    // slots: s = lane + 64k; s<204 heavy, s==255 candidate, rest inert.
    // ring cell c = lane + 64k; colc = active column (== c or c+256 initially)
    int colc[4]; float ringv[4]; int hcol[4]; float hacc[4];
    #pragma unroll
    for (int k = 0; k < 4; ++k) {
        const int c = lane + 64 * k;
        colc[k] = (c >= HB_) ? c : c + 256;            // 204..459
        const int cl = (colc[k] < CB_) ? colc[k] : 0;  // value unused if col>=408
        ringv[k] = accH[cl];
        hcol[k] = (c < HB_) ? c : 0;
        hacc[k] = (c < HB_) ? accH[c] : POSINF;
    }
    const bool v3 = (lane < (HB_ - 192)) || (lane == 63);   // k=3 validity

    asm volatile("s_waitcnt vmcnt(0) lgkmcnt(0)" ::: "memory");   // all init + rows done
    {   // stage row 408 -> A
        u32x4* db = (u32x4*)rowbufA;
        #pragma unroll
        for (int j = 0; j < 4; ++j) db[j * 64 + lane] = p0[j];
    }

    float accc;
    {   // peeled tok = 408 (li = 204): no eviction, identity heavy cols
        ISSUE_ROW(p0, CB_ + 4);   // 412
        const u16* srow = rowbufA;
        float e[4];
        #pragma unroll
        for (int k = 0; k < 4; ++k) {
            const float sg = bf2f(srow[hcol[k]]);
            const bool v = (k < 3) || (lane < (HB_ - 192));   // peel: no candidate
            e[k] = v ? __expf(sg) : 0.f;
        }
        const float presum = wsum64(e[0] + e[1] + e[2] + e[3]);
        const float Z = presum + rsumLDS[0];
        const float invZ = __fdividef(1.f, Z);
        #pragma unroll
        for (int k = 0; k < 4; ++k) hacc[k] = hacc[k] * PEN_ + e[k] * invZ;
        #pragma unroll
        for (int k = 0; k < 4; ++k) {
            const int slot = lane + 64 * k;
            if (slot < HB_) hOutH[slot] = (u16)slot;
        }
        #pragma unroll
        for (int k = 0; k < 4; ++k) {                 // ring: window [204,408]
            const int col = colc[k];
            const float rexp = __expf(bf2f(srow[(col < S_) ? col : 0]));
            const float old = (col == CB_) ? 0.f : ringv[k];
            if (col <= CB_) ringv[k] = old * PEN_ + rexp * invZ;
        }
        // accc = cell col==204 (lane 12, reg 3)
        accc = __int_as_float(__builtin_amdgcn_readlane(__float_as_int(ringv[3]), HB_ & 63));
        #pragma unroll
        for (int k = 0; k < 4; ++k) if (colc[k] == HB_) colc[k] += 256;
        // stage row 409 -> B (p1 drained by prologue vmcnt(0))
        u32x4* db = (u32x4*)rowbufB;
        #pragma unroll
        for (int j = 0; j < 4; ++j) db[j * 64 + lane] = p1[j];
    }

    // One scan step. LD = reg-quad freed by this iter's read (reissued for
    // TOK+4); ST = reg-quad holding row TOK+1 (staged into buf[(TOK+1)&1]).
    #define SCAN_ITER(TOK, LD, ST)                                               \
    do {                                                                         \
        const int _t  = (TOK);                                                   \
        const int _li = _t - RB_;                                                \
        const int _nr = (_t + 4 < S_) ? _t + 4 : S_ - 1;                         \
        ISSUE_ROW(LD, _nr);                                                      \
        WAIT_VM(12);                                                             \
        {   /* stage row TOK+1 */                                                \
            u32x4* _db = (u32x4*)(((_t + 1) & 1) ? rowbufB : rowbufA);           \
            _Pragma("unroll")                                                    \
            for (int _j = 0; _j < 4; ++_j) _db[_j * 64 + lane] = (ST)[_j];       \
        }                                                                        \
        const u16* _srow = (_t & 1) ? rowbufB : rowbufA;                         \
        if (lane == 63) { hcol[3] = _li - 1; hacc[3] = accc; }                   \
        /* keys first: independent of gathers */                                 \
        double _kmin = __hiloint2double(__float_as_int(hacc[0]),                 \
                                        ((2047 - hcol[0]) << 8) | lane);         \
        _Pragma("unroll")                                                        \
        for (int _k = 1; _k < 4; ++_k) {                                         \
            const int _slot = lane + 64 * _k;                                    \
            _kmin = fmin(_kmin, __hiloint2double(__float_as_int(hacc[_k]),       \
                                    ((2047 - hcol[_k]) << 8) | _slot));          \
        }                                                                        \
        _kmin = wmind64(_kmin);                                                  \
        float _e[4];                                                             \
        _Pragma("unroll")                                                        \
        for (int _k = 0; _k < 4; ++_k) {                                         \
            const float _sg = bf2f(_srow[hcol[_k]]);                             \
            const bool _v = (_k < 3) || v3;                                      \
            _e[_k] = _v ? __expf(_sg) : 0.f;                                     \
        }                                                                        \
        float _rexp[4];                                                          \
        _Pragma("unroll")                                                        \
        for (int _k = 0; _k < 4; ++_k)                                           \
            _rexp[_k] = __expf(bf2f(_srow[(colc[_k] < S_) ? colc[_k] : 0]));     \
        const float _presum = wsum64(_e[0] + _e[1] + _e[2] + _e[3]);             \
        const int _ev = __builtin_amdgcn_readlane(__double2loint(_kmin), 63) & 255; \
        const int _kb = _ev >> 6;                                                \
        const float _esel = (_kb == 0) ? _e[0] : (_kb == 1) ? _e[1]              \
                          : (_kb == 2) ? _e[2] : _e[3];                          \
        const float _ebc = __int_as_float(__builtin_amdgcn_readlane(             \
                               __float_as_int(_esel), _ev & 63));                \
        const float _el1 = __int_as_float(__builtin_amdgcn_readlane(             \
                               __float_as_int(_e[3]), 63));                      \
        const float _Z = _presum - _ebc + rsumLDS[_t - CB_];                     \
        const float _invZ = __fdividef(1.f, _Z);                                 \
        _Pragma("unroll")                                                        \
        for (int _k = 0; _k < 4; ++_k) {                                         \
            const int _slot = lane + 64 * _k;                                    \
            const bool _m = (_slot == _ev);                                      \
            hcol[_k] = _m ? (_li - 1) : hcol[_k];                                \
            hacc[_k] = (_m ? accc : hacc[_k]) * PEN_ + (_m ? _el1 : _e[_k]) * _invZ; \
        }                                                                        \
        _Pragma("unroll")                                                        \
        for (int _k = 0; _k < 4; ++_k) {                                         \
            const int _col = colc[_k];                                           \
            const float _old = (_col == _t) ? 0.f : ringv[_k];                   \
            if (_col <= _t) ringv[_k] = _old * PEN_ + _rexp[_k] * _invZ;         \
        }                                                                        \
        const int _kb2 = (_li >> 6) & 3;                                         \
        const float _vsel = (_kb2 == 0) ? ringv[0] : (_kb2 == 1) ? ringv[1]      \
                          : (_kb2 == 2) ? ringv[2] : ringv[3];                   \
        accc = __int_as_float(__builtin_amdgcn_readlane(                         \
                   __float_as_int(_vsel), _li & 63));                            \
        _Pragma("unroll")                                                        \
        for (int _k = 0; _k < 4; ++_k) if (colc[_k] == _li) colc[_k] += 256;     \
        u16* _hrow = hOutH + (size_t)(_t - CB_) * HB_;                           \
        _Pragma("unroll")                                                        \
        for (int _k = 0; _k < 4; ++_k) {                                         \
            const int _slot = lane + 64 * _k;                                    \
            if (_slot < HB_) _hrow[_slot] = (u16)hcol[_k];                       \
        }                                                                        \
    } while (0)

    SCAN_ITER(CB_ + 1, p1, p2);
    SCAN_ITER(CB_ + 2, p2, p3);
    SCAN_ITER(CB_ + 3, p3, p0);
    SCAN_ITER(CB_ + 4, p0, p1);
    for (int tokBase = CB_ + 5; tokBase + 3 < S_; tokBase += 4) {   // 413..2044
        SCAN_ITER(tokBase + 0, p1, p2);
        SCAN_ITER(tokBase + 1, p2, p3);
        SCAN_ITER(tokBase + 2, p3, p0);
        SCAN_ITER(tokBase + 3, p0, p1);
    }
    SCAN_ITER(S_ - 3, p1, p2);
    SCAN_ITER(S_ - 2, p2, p3);
    SCAN_ITER(S_ - 1, p3, p0);
    #undef SCAN_ITER
    #undef ISSUE_ROW
    #undef WAIT_VM
}

// ---------------------------------------------------------------------------
// heavy_merge: rows r>=CB. Gather 204 heavy cols, add to the recent-window
// partial already in O, normalize by (heavy sum + rsumG).
// ---------------------------------------------------------------------------
__global__ __launch_bounds__(256) void heavy_merge(const u16* __restrict__ Sc,
                                                   const float* __restrict__ V,
                                                   const u16* __restrict__ heavyIn,
                                                   const float* __restrict__ rsumG,
                                                   float* __restrict__ O)
{
    const int idx = blockIdx.x;
    const int r = CB_ + (idx >> 4), h = idx & 15;
    const int tid = threadIdx.x;
    const int lane = tid & 63, wave = tid >> 6;
    __shared__ float sbuf[208];
    __shared__ u16 cbuf[208];
    __shared__ float wred[4];
    __shared__ float opart[4][64];
    const u16* srow = Sc + ((size_t)h * S_ + r) * S_;
    const u16* hrow = heavyIn + ((size_t)h * NSCAN_ + (r - CB_)) * HB_;
    float ls = 0.f;
    for (int i = tid; i < HB_; i += 256) {
        const int col = hrow[i];
        const float p = __expf(bf2f(srow[col]));
        sbuf[i] = p; cbuf[i] = (u16)col;
        ls += p;
    }
    ls = wsum64(ls);
    if (lane == 0) wred[wave] = ls;
    __syncthreads();
    const float Z = wred[0] + wred[1] + wred[2] + wred[3]
                  + rsumG[(size_t)h * NSCAN_ + r - CB_];
    float pv = 0.f;
    const float* vh = V + (size_t)h * S_ * D_;
    for (int i = wave; i < HB_; i += 4)
        pv += sbuf[i] * vh[(size_t)cbuf[i] * D_ + lane];
    opart[wave][lane] = pv;
    __syncthreads();
    if (tid < 64) {
        const float tot = opart[0][tid] + opart[1][tid] + opart[2][tid] + opart[3][tid];
        float* op = &O[(size_t)r * E_ + h * D_ + tid];
        *op = (*op + tot) / Z;
    }
}

// ---------------------------------------------------------------------------
extern "C" void kernel_launch(void* const* d_in, const int* in_sizes, int n_in,
                              void* d_out, int out_size, void* d_ws, size_t ws_size,
                              hipStream_t stream)
{
    const float* hs = (const float*)d_in[0];
    const float* Wq = (const float*)d_in[2];
    const float* bq = (const float*)d_in[3];
    const float* Wk = (const float*)d_in[4];
    const float* bk = (const float*)d_in[5];
    const float* Wv = (const float*)d_in[6];
    const float* bv = (const float*)d_in[7];
    const float* Wo = (const float*)d_in[8];
    const float* bo = (const float*)d_in[9];

    char* ws = (char*)d_ws;
    const size_t MB = 1024 * 1024;
    float* Q     = (float*)(ws);                   //   8 MB [H][S][D]
    float* K     = (float*)(ws + 8 * MB);          //   8 MB
    float* V     = (float*)(ws + 16 * MB);         //   8 MB
    u16*   Sc    = (u16*)  (ws + 24 * MB);         // 128 MB [H][S][S] bf16
    u16*   hvy   = (u16*)  (ws + 152 * MB);        // ~10.2 MB [H][NSCAN][HB]
    float* rsumG = (float*)(ws + 163 * MB);        // 105 KB [H][NSCAN]
    float* accG  = (float*)(ws + 164 * MB);        //  26 KB [H][CB]
    float* O     = (float*)(ws + 168 * MB);        //   8 MB [S][E]
    (void)ws_size; (void)in_sizes; (void)n_in; (void)out_size;

    (void)hipMemsetAsync(accG, 0, (size_t)H_ * CB_ * sizeof(float), stream);
    qkv_gemm<<<dim3(8, 16, 3), 256, 0, stream>>>(hs, Wq, bq, Wk, bk, Wv, bv, Q, K, V);
    sc_gemm <<<dim3(32, 32, 16), 256, 0, stream>>>(Q, K, Sc);
    prep_kernel<<<dim3(NSCAN_ / 4 + CB_ / 4, H_), 256, 0, stream>>>(Sc, rsumG, accG);
    scan_fill<<<16 + NFULL_ + NPART_, 256, 0, stream>>>(Sc, accG, rsumG, hvy, V, O);
    heavy_merge<<<NPART_, 256, 0, stream>>>(Sc, V, hvy, rsumG, O);
    proj_gemm<<<dim3(8, 16, 1), 256, 0, stream>>>(O, Wo, bo, (float*)d_out);
}

// Round 8
// 1764.659 us; speedup vs baseline: 1.0909x; 1.0143x over previous
//
#include <hip/hip_runtime.h>

#define S_ 2048
#define E_ 1024
#define H_ 16
#define D_ 64
#define HB_ 204
#define RB_ 204
#define CB_ 408
#define NSCAN_ (S_ - CB_)
#define PEN_ 0.99f
#define NEGINF (-__builtin_huge_valf())
#define POSINF (__builtin_huge_valf())

typedef unsigned short u16;
typedef unsigned int u32;
typedef unsigned int u32x4 __attribute__((ext_vector_type(4)));

__device__ __forceinline__ float bf2f(u16 u) {
    union { u32 u; float f; } a; a.u = ((u32)u) << 16; return a.f;
}
__device__ __forceinline__ u16 f2bf(float f) {
    union { float f; u32 u; } a; a.f = f;
    u32 r = (a.u + 0x7FFFu + ((a.u >> 16) & 1u)) >> 16;
    return (u16)r;
}

// ---------------------------------------------------------------------------
// Wave64 reductions via DPP.
// wsum64 / wsum64_63: sum (broadcast / lane-63-valid).
// wmind64: key-only f64 min (lane 63). wminp64: f64 min + f32 payload (lane 63).
// ---------------------------------------------------------------------------
#define DPPF(ID, V, CTRL, RMASK) \
    __int_as_float(__builtin_amdgcn_update_dpp(__float_as_int(ID), __float_as_int(V), CTRL, RMASK, 0xf, false))

__device__ __forceinline__ float wsum64_63(float v) {
    float t;
    t = DPPF(0.f, v, 0x111, 0xf); v += t;
    t = DPPF(0.f, v, 0x112, 0xf); v += t;
    t = DPPF(0.f, v, 0x114, 0xf); v += t;
    t = DPPF(0.f, v, 0x118, 0xf); v += t;
    t = DPPF(0.f, v, 0x142, 0xa); v += t;
    t = DPPF(0.f, v, 0x143, 0xc); v += t;
    return v;                        // lane 63 holds the wave total
}
__device__ __forceinline__ float wsum64(float v) {
    v = wsum64_63(v);
    return __int_as_float(__builtin_amdgcn_readlane(__float_as_int(v), 63));
}
template <int CTRL, int RMASK>
__device__ __forceinline__ double dmin_step(double v) {
    const int lo = __double2loint(v), hi = __double2hiint(v);
    const int slo = __builtin_amdgcn_update_dpp(0, lo, CTRL, RMASK, 0xf, false);
    const int shi = __builtin_amdgcn_update_dpp(0x7FF00000, hi, CTRL, RMASK, 0xf, false);
    return fmin(v, __hiloint2double(shi, slo));
}
__device__ __forceinline__ double wmind64(double v) {
    v = dmin_step<0x111, 0xf>(v);
    v = dmin_step<0x112, 0xf>(v);
    v = dmin_step<0x114, 0xf>(v);
    v = dmin_step<0x118, 0xf>(v);
    v = dmin_step<0x142, 0xa>(v);
    v = dmin_step<0x143, 0xc>(v);
    return v;
}
// payload variant: identity key=+inf (never selected vs finite), payload rides.
template <int CTRL, int RMASK>
__device__ __forceinline__ void dminp_step(double& v, float& p) {
    const int lo = __double2loint(v), hi = __double2hiint(v);
    const int slo = __builtin_amdgcn_update_dpp(0, lo, CTRL, RMASK, 0xf, false);
    const int shi = __builtin_amdgcn_update_dpp(0x7FF00000, hi, CTRL, RMASK, 0xf, false);
    const int spi = __builtin_amdgcn_update_dpp(0, __float_as_int(p), CTRL, RMASK, 0xf, false);
    const double sv = __hiloint2double(shi, slo);
    if (sv < v) { v = sv; p = __int_as_float(spi); }
}
__device__ __forceinline__ void wminp64(double& v, float& p) {
    dminp_step<0x111, 0xf>(v, p);
    dminp_step<0x112, 0xf>(v, p);
    dminp_step<0x114, 0xf>(v, p);
    dminp_step<0x118, 0xf>(v, p);
    dminp_step<0x142, 0xa>(v, p);   // row_bcast15
    dminp_step<0x143, 0xc>(v, p);   // row_bcast31
}

// ---------------------------------------------------------------------------
// QKV projection: X[S,E] @ W^T + b -> head-major [H][S][D] f32.
// ---------------------------------------------------------------------------
__global__ __launch_bounds__(256) void qkv_gemm(
    const float* __restrict__ X,
    const float* __restrict__ W0, const float* __restrict__ b0,
    const float* __restrict__ W1, const float* __restrict__ b1,
    const float* __restrict__ W2, const float* __restrict__ b2,
    float* __restrict__ Q, float* __restrict__ K, float* __restrict__ V)
{
    const int z = blockIdx.z;
    const float* W    = (z == 0) ? W0 : (z == 1) ? W1 : W2;
    const float* bias = (z == 0) ? b0 : (z == 1) ? b1 : b2;
    float* dst        = (z == 0) ? Q  : (z == 1) ? K  : V;
    const int o0 = blockIdx.x * 128, s0 = blockIdx.y * 128;
    __shared__ float As[16][132];   // [k][m]
    __shared__ float Bs[16][132];   // [k][n]
    const int tid = threadIdx.x;
    const int ty = tid >> 4, tx = tid & 15;
    const int r = tid >> 1, kq = (tid & 1) << 3;
    float acc[8][8] = {};
    for (int kb = 0; kb < E_; kb += 16) {
        float4 a0 = *(const float4*)&X[(size_t)(s0 + r) * E_ + kb + kq];
        float4 a1 = *(const float4*)&X[(size_t)(s0 + r) * E_ + kb + kq + 4];
        float4 w0 = *(const float4*)&W[(size_t)(o0 + r) * E_ + kb + kq];
        float4 w1 = *(const float4*)&W[(size_t)(o0 + r) * E_ + kb + kq + 4];
        __syncthreads();
        As[kq+0][r]=a0.x; As[kq+1][r]=a0.y; As[kq+2][r]=a0.z; As[kq+3][r]=a0.w;
        As[kq+4][r]=a1.x; As[kq+5][r]=a1.y; As[kq+6][r]=a1.z; As[kq+7][r]=a1.w;
        Bs[kq+0][r]=w0.x; Bs[kq+1][r]=w0.y; Bs[kq+2][r]=w0.z; Bs[kq+3][r]=w0.w;
        Bs[kq+4][r]=w1.x; Bs[kq+5][r]=w1.y; Bs[kq+6][r]=w1.z; Bs[kq+7][r]=w1.w;
        __syncthreads();
        #pragma unroll
        for (int kk = 0; kk < 16; ++kk) {
            float av[8], bv[8];
            *(float4*)&av[0] = *(const float4*)&As[kk][ty * 8];
            *(float4*)&av[4] = *(const float4*)&As[kk][ty * 8 + 4];
            *(float4*)&bv[0] = *(const float4*)&Bs[kk][tx * 8];
            *(float4*)&bv[4] = *(const float4*)&Bs[kk][tx * 8 + 4];
            #pragma unroll
            for (int i = 0; i < 8; ++i)
                #pragma unroll
                for (int j = 0; j < 8; ++j) acc[i][j] += av[i] * bv[j];
        }
    }
    #pragma unroll
    for (int i = 0; i < 8; ++i) {
        const int s = s0 + ty * 8 + i;
        #pragma unroll
        for (int jq = 0; jq < 2; ++jq) {
            const int o = o0 + tx * 8 + jq * 4;
            float4 v;
            v.x = acc[i][jq*4+0] + bias[o+0];
            v.y = acc[i][jq*4+1] + bias[o+1];
            v.z = acc[i][jq*4+2] + bias[o+2];
            v.w = acc[i][jq*4+3] + bias[o+3];
            if (z == 0) { v.x *= 0.125f; v.y *= 0.125f; v.z *= 0.125f; v.w *= 0.125f; }
            *(float4*)&dst[((size_t)(o >> 6) * S_ + s) * D_ + (o & 63)] = v;
        }
    }
}

// ---------------------------------------------------------------------------
// Output projection: Y[S,E] = X[S,E] @ Wo^T + bo
// ---------------------------------------------------------------------------
__global__ __launch_bounds__(256) void proj_gemm(
    const float* __restrict__ X, const float* __restrict__ W,
    const float* __restrict__ bias, float* __restrict__ Y)
{
    const int o0 = blockIdx.x * 128, s0 = blockIdx.y * 128;
    __shared__ float As[16][132];
    __shared__ float Bs[16][132];
    const int tid = threadIdx.x;
    const int ty = tid >> 4, tx = tid & 15;
    const int r = tid >> 1, kq = (tid & 1) << 3;
    float acc[8][8] = {};
    for (int kb = 0; kb < E_; kb += 16) {
        float4 a0 = *(const float4*)&X[(size_t)(s0 + r) * E_ + kb + kq];
        float4 a1 = *(const float4*)&X[(size_t)(s0 + r) * E_ + kb + kq + 4];
        float4 w0 = *(const float4*)&W[(size_t)(o0 + r) * E_ + kb + kq];
        float4 w1 = *(const float4*)&W[(size_t)(o0 + r) * E_ + kb + kq + 4];
        __syncthreads();
        As[kq+0][r]=a0.x; As[kq+1][r]=a0.y; As[kq+2][r]=a0.z; As[kq+3][r]=a0.w;
        As[kq+4][r]=a1.x; As[kq+5][r]=a1.y; As[kq+6][r]=a1.z; As[kq+7][r]=a1.w;
        Bs[kq+0][r]=w0.x; Bs[kq+1][r]=w0.y; Bs[kq+2][r]=w0.z; Bs[kq+3][r]=w0.w;
        Bs[kq+4][r]=w1.x; Bs[kq+5][r]=w1.y; Bs[kq+6][r]=w1.z; Bs[kq+7][r]=w1.w;
        __syncthreads();
        #pragma unroll
        for (int kk = 0; kk < 16; ++kk) {
            float av[8], bv[8];
            *(float4*)&av[0] = *(const float4*)&As[kk][ty * 8];
            *(float4*)&av[4] = *(const float4*)&As[kk][ty * 8 + 4];
            *(float4*)&bv[0] = *(const float4*)&Bs[kk][tx * 8];
            *(float4*)&bv[4] = *(const float4*)&Bs[kk][tx * 8 + 4];
            #pragma unroll
            for (int i = 0; i < 8; ++i)
                #pragma unroll
                for (int j = 0; j < 8; ++j) acc[i][j] += av[i] * bv[j];
        }
    }
    #pragma unroll
    for (int i = 0; i < 8; ++i) {
        const int s = s0 + ty * 8 + i;
        #pragma unroll
        for (int jq = 0; jq < 2; ++jq) {
            const int o = o0 + tx * 8 + jq * 4;
            float4 v;
            v.x = acc[i][jq*4+0] + bias[o+0];
            v.y = acc[i][jq*4+1] + bias[o+1];
            v.z = acc[i][jq*4+2] + bias[o+2];
            v.w = acc[i][jq*4+3] + bias[o+3];
            *(float4*)&Y[(size_t)s * E_ + o] = v;
        }
    }
}

// ---------------------------------------------------------------------------
// Sc[h][i][j] = Q[h][i] . K[h][j] (bf16). Lower-tri tiles only. k-major LDS.
// ---------------------------------------------------------------------------
__global__ __launch_bounds__(256) void sc_gemm(const float* __restrict__ Q,
                                               const float* __restrict__ K,
                                               u16* __restrict__ Sc)
{
    const int h = blockIdx.z;
    const int jt = blockIdx.x, it = blockIdx.y;
    if (jt > it) return;
    const int i0 = it * 64, j0 = jt * 64;
    __shared__ float Qs[64][65];   // [k][m]
    __shared__ float Ks[64][65];   // [k][n]
    const float* Qh = Q + (size_t)h * S_ * D_;
    const float* Kh = K + (size_t)h * S_ * D_;
    const int tid = threadIdx.x;
    for (int idx = tid; idx < 1024; idx += 256) {
        const int rr = idx >> 4, c4 = (idx & 15) << 2;
        float4 q4 = *(const float4*)&Qh[(size_t)(i0 + rr) * D_ + c4];
        Qs[c4 + 0][rr] = q4.x; Qs[c4 + 1][rr] = q4.y; Qs[c4 + 2][rr] = q4.z; Qs[c4 + 3][rr] = q4.w;
        float4 k4 = *(const float4*)&Kh[(size_t)(j0 + rr) * D_ + c4];
        Ks[c4 + 0][rr] = k4.x; Ks[c4 + 1][rr] = k4.y; Ks[c4 + 2][rr] = k4.z; Ks[c4 + 3][rr] = k4.w;
    }
    __syncthreads();
    const int ty = tid >> 4, tx = tid & 15;
    float acc[4][4] = {};
    #pragma unroll 4
    for (int kk = 0; kk < 64; ++kk) {
        float4 a4 = *(const float4*)&Qs[kk][ty * 4];
        float4 b4 = *(const float4*)&Ks[kk][tx * 4];
        const float av[4] = {a4.x, a4.y, a4.z, a4.w};
        const float bv[4] = {b4.x, b4.y, b4.z, b4.w};
        #pragma unroll
        for (int i = 0; i < 4; ++i)
            #pragma unroll
            for (int j = 0; j < 4; ++j) acc[i][j] += av[i] * bv[j];
    }
    u16* out = Sc + ((size_t)h * S_ + i0) * S_ + j0;
    #pragma unroll
    for (int i = 0; i < 4; ++i)
        #pragma unroll
        for (int j = 0; j < 4; ++j)
            out[(size_t)(ty * 4 + i) * S_ + tx * 4 + j] = f2bf(acc[i][j]);
}

// ---------------------------------------------------------------------------
// prep_kernel: rsum per scan row + acc-init over rows 0..407 (global atomics).
// ---------------------------------------------------------------------------
__global__ __launch_bounds__(256) void prep_kernel(const u16* __restrict__ Sc,
                                                   float* __restrict__ rsumG,
                                                   float* __restrict__ accG)
{
    const int h = blockIdx.y;
    const int wave = threadIdx.x >> 6, lane = threadIdx.x & 63;
    const int bx = blockIdx.x;
    if (bx < NSCAN_ / 4) {
        const int tok = CB_ + bx * 4 + wave;
        const u16* row = Sc + ((size_t)h * S_ + tok) * S_ + (tok - RB_);
        float sm = 0.f;
        #pragma unroll
        for (int k = 0; k < 4; ++k) {
            const int j = k * 64 + lane;
            if (j <= RB_) sm += __expf(bf2f(row[j]));
        }
        const float z = wsum64(sm);
        if (lane == 0) rsumG[(size_t)h * NSCAN_ + tok - CB_] = z;
    } else {
        const int t = (bx - NSCAN_ / 4) * 4 + wave;   // 0..407
        const u16* row = Sc + ((size_t)h * S_ + t) * S_;
        float sm = 0.f;
        for (int c = lane; c <= t; c += 64) sm += __expf(bf2f(row[c]));
        const float z = wsum64(sm);
        const float w = __powf(PEN_, (float)(CB_ - 1 - t)) / z;
        for (int c = lane; c <= t; c += 64)
            atomicAdd(&accG[h * CB_ + c], __expf(bf2f(row[c])) * w);
    }
}

// ---------------------------------------------------------------------------
// MERGED kernel. R7: R4's proven 4-wave 1-barrier scan shell, plus two
// chain cuts whose pieces are individually validated:
//  r7a. wminp64 payload: evicted slot's exp rides with the key -> the
//       post-combine {ds_read srow[hev] -> exp} leaves the loop-carried
//       chain. Numerics validated by R5's PASS (Z bit-identical: pm == e).
//  r7b. CORRECT speculation (R5's bug fixed): phase B(t) issues ds_reads
//       from row t+1's buffer with the PRE-update hcol plus 4 static
//       uniform columns (li-1 evictee-next, li cand-next, li+1 ew0-next,
//       li+1+tid ring-next); lane ev(t) is repaired by a select vs the
//       uniform fixE exp. Values bit-identical to R4's, one iter early.
//       Phase B then reads ONLY buffer (t+1)%3 (stage target is (t+2)%3)
//       so the single barrier still orders everything.
//  r7c. Staging ledger made truly count-robust: iter t stages row t+2 and
//       reissues the SAME quad for row t+6 -> at WAIT_VM(3) there are
//       always >=3 newer LOADS (t+3,t+4,t+5), independent of stores.
//       Peel/ramp (408-412) use full vmcnt(0) drains + R4's proven
//       2-barrier body; a priming block computes iter-413's registers.
// ---------------------------------------------------------------------------
#define NFULL_ (CB_ * H_)          /* 6528  full-attn blocks (r<CB)  */
#define NPART_ (NSCAN_ * H_)       /* 26240 recent-partial blocks    */

__global__ __launch_bounds__(256) void scan_fill(const u16* __restrict__ Sc,
                                                 const float* __restrict__ accG,
                                                 const float* __restrict__ rsumG,
                                                 u16* __restrict__ heavyOut,
                                                 const float* __restrict__ V,
                                                 float* __restrict__ O)
{
    __shared__ __align__(16) char ldsPool[20096];
    const int bid = blockIdx.x;
    const int tid = threadIdx.x;

    if (bid >= 16) {
        // ---------------- fill paths: dense attention work ----------------
        float* sbuf  = (float*)ldsPool;            // up to 416 f32
        float* wred  = (float*)(ldsPool + 1664);   // 4 f32
        float* opart = (float*)(ldsPool + 1696);   // 256 f32
        const int lane = tid & 63, wave = tid >> 6;
        int h, r, c0, n;
        bool partial;
        if (bid < 16 + NFULL_) {                   // r < CB: full causal row
            const int t2 = bid - 16;
            r = t2 >> 4; h = t2 & 15;
            c0 = 0; n = r + 1; partial = false;
        } else {                                   // r >= CB: recent window only
            const int idx = bid - 16 - NFULL_;
            r = CB_ + (idx >> 4); h = idx & 15;
            c0 = r - RB_; n = RB_ + 1; partial = true;
        }
        const u16* srow = Sc + ((size_t)h * S_ + r) * S_;
        float ls = 0.f;
        for (int i = tid; i < n; i += 256) {
            const float p = __expf(bf2f(srow[c0 + i]));
            sbuf[i] = p; ls += p;
        }
        ls = wsum64(ls);
        if (lane == 0) wred[wave] = ls;
        __syncthreads();
        const float Z = wred[0] + wred[1] + wred[2] + wred[3];
        float pv = 0.f;
        const float* vh = V + (size_t)h * S_ * D_;
        for (int i = wave; i < n; i += 4)
            pv += sbuf[i] * vh[(size_t)(c0 + i) * D_ + lane];
        opart[wave * 64 + lane] = pv;
        __syncthreads();
        if (tid < 64) {
            const float tot = opart[tid] + opart[64 + tid] + opart[128 + tid] + opart[192 + tid];
            // partial rows: store UNNORMALIZED; heavy_merge adds + divides
            O[(size_t)r * E_ + h * D_ + tid] = partial ? tot : (tot / Z);
        }
        return;
    }

    // ---------------- scan path: 4 waves, one slot per thread ----------------
    __builtin_amdgcn_s_setprio(3);
    const int h = bid;
    const int lane = tid & 63, wv = tid >> 6;
    float*  ring    = (float*)ldsPool;             // 256 f32 (1024 B)
    float*  rsumLDS = (float*)(ldsPool + 1024);    // NSCAN f32 (6560 B)
    u16*    buf_0   = (u16*)(ldsPool + 7584);      // 4096 B (rows tok%3==0)
    u16*    buf_1   = (u16*)(ldsPool + 11680);     // 4096 B
    u16*    buf_2   = (u16*)(ldsPool + 15776);     // 4096 B
    float*  wredL   = (float*)(ldsPool + 19872);   // 2 x 4 f32 (parity)
    double* kredL   = (double*)(ldsPool + 19904);  // 2 x 4 f64 (parity)
    float*  payL    = (float*)(ldsPool + 19968);   // 2 x 4 f32 (parity)
    float*  el1L    = (float*)(ldsPool + 20000);   // 2 f32 (ramp only)
    const u16* sch = Sc + (size_t)h * S_ * S_;
    const float* accH = accG + h * CB_;
    u16* hOutH = heavyOut + (size_t)h * NSCAN_ * HB_;

    const bool vHeavy = (tid < HB_);
    const bool vRing  = (tid <= RB_);
    const bool vCand  = (tid == 255);

    u32x4 p0, p1, p2, p3;
    #define ISSUE1(BUF, ROWI)                                                 \
        do {                                                                  \
            const void* _ap = (const void*)((const char*)(sch + (size_t)(ROWI) * S_) + tid * 16); \
            asm volatile("global_load_dwordx4 %0, %1, off"                    \
                         : "=&v"(BUF) : "v"(_ap) : "memory");                 \
        } while (0)
    #define WAIT_VM(N) asm volatile("s_waitcnt vmcnt(" #N ")" ::: "memory")
    #define SBAR() asm volatile("s_waitcnt lgkmcnt(0)\n\ts_barrier" ::: "memory")

    ISSUE1(p0, CB_ + 0);   // 408
    ISSUE1(p1, CB_ + 1);   // 409
    ISSUE1(p2, CB_ + 2);   // 410
    ISSUE1(p3, CB_ + 3);   // 411

    for (int i = tid; i < NSCAN_; i += 256) rsumLDS[i] = rsumG[(size_t)h * NSCAN_ + i];
    for (int c = HB_ + tid; c < CB_; c += 256) ring[c & 255] = accH[c];
    int   hcol = vHeavy ? tid : 0;
    float hacc = vHeavy ? accH[tid] : POSINF;
    float accc;
    // steady-state carried registers (primed before the steady loop)
    float e_cur, el1_cur, ew0_cur, expw_cur, rsum_cur;

    __syncthreads();                 // init visible; drains all loads
    ((u32x4*)buf_0)[tid] = p0;       // row 408
    ISSUE1(p0, CB_ + 4);             // 412
    ((u32x4*)buf_1)[tid] = p1;       // row 409
    ISSUE1(p1, CB_ + 5);             // 413
    __syncthreads();                 // buf0/1 visible; drains 412/413

    {   // peeled tok = 408 (li = 204): no eviction (R4-proven form)
        ((u32x4*)buf_2)[tid] = p2;   // row 410 (drained by first sync)
        ISSUE1(p2, CB_ + 6);         // 414
        const u16* srow = buf_0;
        const float sg = bf2f(srow[hcol]);
        const float e  = vHeavy ? __expf(sg) : 0.f;
        const float ls = wsum64_63(e);
        if (lane == 63) wredL[wv] = ls;
        float oldw = 0.f, expw = 0.f;
        if (vRing) {
            expw = __expf(bf2f(srow[HB_ + tid]));
            oldw = (tid == RB_) ? 0.f : ring[(HB_ + tid) & 255];
        }
        __syncthreads();
        const float4 ws = *(const float4*)wredL;
        const float Z = ws.x + ws.y + ws.z + ws.w + rsumLDS[0];
        const float invZ = __fdividef(1.f, Z);
        hacc = hacc * PEN_ + e * invZ;
        if (vHeavy) hOutH[tid] = (u16)tid;
        if (vRing)  ring[(HB_ + tid) & 255] = oldw * PEN_ + expw * invZ;
        __syncthreads();
        accc = ring[HB_ & 255];
    }

    // ---- ramp iters 409-412: R4-proven 2-barrier body, full vm drains ----
    // RSTEP(TOK, Q, DBUF, SBUF, P): stage row TOK+2 (in Q) -> DBUF, reissue
    // Q <- row TOK+6; compute on SBUF (row TOK).
    #define RSTEP(TOK, Q, DBUF, SBUF, P)                                         \
    do {                                                                         \
        const int _t  = (TOK);                                                   \
        const int _li = _t - RB_;                                                \
        asm volatile("s_waitcnt vmcnt(0)" ::: "memory");                         \
        ((u32x4*)(DBUF))[tid] = Q;                                               \
        ISSUE1(Q, _t + 6);                                                       \
        const u16* _sr = (const u16*)(SBUF);                                     \
        const int   _hc = vCand ? (_li - 1) : hcol;                              \
        const float _ha = vCand ? accc : hacc;                                   \
        const float _sg = bf2f(_sr[_hc]);                                        \
        float _expw = 0.f;                                                       \
        if (vRing) _expw = __expf(bf2f(_sr[_li + tid]));                         \
        const float _e = (vHeavy || vCand) ? __expf(_sg) : 0.f;                  \
        const float _ls = wsum64_63(_e);                                         \
        double _key = __hiloint2double(__float_as_int(_ha),                      \
                                       ((2047 - _hc) << 8) | tid);               \
        _key = wmind64(_key);                                                    \
        if (lane == 63) {                                                        \
            wredL[(P)*4+wv] = _ls;                                               \
            kredL[(P)*4+wv] = _key;                                              \
            if (wv == 3) el1L[P] = _e;                                           \
        }                                                                        \
        __syncthreads();                                                         \
        const float4 _w4 = *(const float4*)&wredL[(P)*4];                        \
        const double _km = fmin(fmin(kredL[(P)*4+0], kredL[(P)*4+1]),            \
                                fmin(kredL[(P)*4+2], kredL[(P)*4+3]));           \
        const int _lo  = __double2loint(_km);                                    \
        const int _ev  = _lo & 255;                                              \
        const int _hev = 2047 - (_lo >> 8);                                      \
        const float _ebc = __expf(bf2f(_sr[_hev]));                              \
        const float _el1 = el1L[P];                                              \
        const float _rs = rsumLDS[_t - CB_];                                     \
        const float _Z = (_w4.x + _w4.y + _w4.z + _w4.w) - _ebc + _rs;           \
        const float _invZ = __fdividef(1.f, _Z);                                 \
        const float _oldw0 = ring[_li & 255];                                    \
        if (vRing && tid != 0) {                                                 \
            const float _oldw = (tid == RB_) ? 0.f : ring[(_li + tid) & 255];    \
            ring[(_li + tid) & 255] = _oldw * PEN_ + _expw * _invZ;              \
        }                                                                        \
        const bool _m = (tid == _ev);                                            \
        hcol = _m ? (_li - 1) : _hc;                                             \
        hacc = (_m ? accc : _ha) * PEN_ + (_m ? _el1 : _e) * _invZ;              \
        const float _ew0 = __expf(bf2f(_sr[_li]));                               \
        accc = _oldw0 * PEN_ + _ew0 * _invZ;                                     \
        if (vHeavy) hOutH[(size_t)(_t - CB_) * HB_ + tid] = (u16)hcol;           \
        __syncthreads();                                                         \
    } while (0)

    RSTEP(CB_ + 1, p3, buf_0, buf_1, 1);   // 409: stage 411->buf0, issue 415
    RSTEP(CB_ + 2, p0, buf_1, buf_2, 0);   // 410: stage 412->buf1, issue 416
    RSTEP(CB_ + 3, p1, buf_2, buf_0, 1);   // 411: stage 413->buf2, issue 417
    RSTEP(CB_ + 4, p2, buf_0, buf_1, 0);   // 412: stage 414->buf0, issue 418
    #undef RSTEP

    {   // ---- priming for steady iter 413 (buf2 = row 413; post-412 state) ----
        const u16* rt = buf_2;
        const int li = CB_ + 5 - RB_;                      // 209
        const float fixC = __expf(bf2f(rt[li - 1]));       // candidate e
        const float sg = bf2f(rt[hcol]);
        e_cur   = vCand ? fixC : (vHeavy ? __expf(sg) : 0.f);
        el1_cur = fixC;
        ew0_cur = __expf(bf2f(rt[li]));
        expw_cur = vRing ? __expf(bf2f(rt[li + tid])) : 0.f;
        rsum_cur = rsumLDS[CB_ + 5 - CB_];
    }

    // ---- steady body: 1 barrier; spec'd e/expw/ew0 in registers ----
    #define STEP(TOK, Q, DBUF, SNBUF, P)                                         \
    do {                                                                         \
        const int _t  = (TOK);                                                   \
        const int _li = _t - RB_;                                                \
        if (_t + 2 < S_) {                                                       \
            WAIT_VM(3);                                                          \
            ((u32x4*)(DBUF))[tid] = Q;                                           \
            ISSUE1(Q, (_t + 6 < S_) ? _t + 6 : S_ - 1);                          \
        }                                                                        \
        const float _ls = wsum64_63(e_cur);                                      \
        const int   _kc = vCand ? (_li - 1) : hcol;                              \
        const float _ka = vCand ? accc : hacc;                                   \
        double _key = __hiloint2double(__float_as_int(_ka),                      \
                                       ((2047 - _kc) << 8) | tid);               \
        float _pay = e_cur;                                                      \
        wminp64(_key, _pay);                                                     \
        if (lane == 63) {                                                        \
            wredL[(P)*4+wv] = _ls;                                               \
            kredL[(P)*4+wv] = _key;                                              \
            payL[(P)*4+wv]  = _pay;                                              \
        }                                                                        \
        SBAR();                                                                  \
        const u16* _rn = (const u16*)(SNBUF);                                    \
        const u16 _sgq  = _rn[_kc & 2047];                                       \
        const u16 _sgE  = _rn[(_li - 1) & 2047];                                 \
        const u16 _sgC  = _rn[_li & 2047];                                       \
        const u16 _sgW0 = _rn[(_li + 1) & 2047];                                 \
        const u16 _sgRW = _rn[(_li + 1 + tid) & 2047];                           \
        const float4 _w4 = *(const float4*)&wredL[(P)*4];                        \
        double _k0 = kredL[(P)*4+0], _k1 = kredL[(P)*4+1];                       \
        double _k2 = kredL[(P)*4+2], _k3 = kredL[(P)*4+3];                       \
        float  _q0 = payL[(P)*4+0], _q1 = payL[(P)*4+1];                         \
        float  _q2 = payL[(P)*4+2], _q3 = payL[(P)*4+3];                         \
        const float _oldw0 = ring[_li & 255];                                    \
        float _oldw = 0.f;                                                       \
        if (vRing) _oldw = (tid == RB_) ? 0.f : ring[(_li + tid) & 255];         \
        double _km = _k0; float _pm = _q0;                                       \
        if (_k1 < _km) { _km = _k1; _pm = _q1; }                                 \
        if (_k2 < _km) { _km = _k2; _pm = _q2; }                                 \
        if (_k3 < _km) { _km = _k3; _pm = _q3; }                                 \
        const int _ev = __double2loint(_km) & 255;                               \
        const float _Z = _w4.x + _w4.y + _w4.z + _w4.w - _pm + rsum_cur;         \
        const float _invZ = __fdividef(1.f, _Z);                                 \
        const bool _m = (tid == _ev);                                            \
        hacc = (_m ? accc : _ka) * PEN_ + (_m ? el1_cur : e_cur) * _invZ;        \
        hcol = _m ? (_li - 1) : _kc;                                             \
        if (vRing && tid != 0)                                                   \
            ring[(_li + tid) & 255] = _oldw * PEN_ + expw_cur * _invZ;           \
        accc = _oldw0 * PEN_ + ew0_cur * _invZ;                                  \
        if (vHeavy) hOutH[(size_t)(_t - CB_) * HB_ + tid] = (u16)hcol;           \
        const float _eS = __expf(bf2f(_sgq));                                    \
        const float _eE = __expf(bf2f(_sgE));                                    \
        const float _eC = __expf(bf2f(_sgC));                                    \
        e_cur   = vCand ? _eC : (vHeavy ? (_m ? _eE : _eS) : 0.f);               \
        el1_cur = _eC;                                                           \
        ew0_cur = __expf(bf2f(_sgW0));                                           \
        expw_cur = vRing ? __expf(bf2f(_sgRW)) : 0.f;                            \
        rsum_cur = (_t + 1 - CB_ < NSCAN_) ? rsumLDS[_t + 1 - CB_] : 0.f;        \
    } while (0)

    for (int t0 = CB_ + 5; t0 + 11 <= S_ - 4; t0 += 12) {   // 413..2044
        STEP(t0 + 0,  p3, buf_1, buf_0, 1);
        STEP(t0 + 1,  p0, buf_2, buf_1, 0);
        STEP(t0 + 2,  p1, buf_0, buf_2, 1);
        STEP(t0 + 3,  p2, buf_1, buf_0, 0);
        STEP(t0 + 4,  p3, buf_2, buf_1, 1);
        STEP(t0 + 5,  p0, buf_0, buf_2, 0);
        STEP(t0 + 6,  p1, buf_1, buf_0, 1);
        STEP(t0 + 7,  p2, buf_2, buf_1, 0);
        STEP(t0 + 8,  p3, buf_0, buf_2, 1);
        STEP(t0 + 9,  p0, buf_1, buf_0, 0);
        STEP(t0 + 10, p1, buf_2, buf_1, 1);
        STEP(t0 + 11, p2, buf_0, buf_2, 0);
    }
    STEP(S_ - 3, p3, buf_1, buf_0, 1);   // 2045: stage 2047, issue (clamped)
    STEP(S_ - 2, p0, buf_2, buf_1, 0);   // 2046: stage skipped (guard)
    STEP(S_ - 1, p1, buf_0, buf_2, 1);   // 2047: stage skipped (guard)
    #undef STEP
    #undef ISSUE1
    #undef WAIT_VM
    #undef SBAR
}

// ---------------------------------------------------------------------------
// heavy_merge: rows r>=CB. Gather 204 heavy cols, add to the recent-window
// partial already in O, normalize by (heavy sum + rsumG).
// ---------------------------------------------------------------------------
__global__ __launch_bounds__(256) void heavy_merge(const u16* __restrict__ Sc,
                                                   const float* __restrict__ V,
                                                   const u16* __restrict__ heavyIn,
                                                   const float* __restrict__ rsumG,
                                                   float* __restrict__ O)
{
    const int idx = blockIdx.x;
    const int r = CB_ + (idx >> 4), h = idx & 15;
    const int tid = threadIdx.x;
    const int lane = tid & 63, wave = tid >> 6;
    __shared__ float sbuf[208];
    __shared__ u16 cbuf[208];
    __shared__ float wred[4];
    __shared__ float opart[4][64];
    const u16* srow = Sc + ((size_t)h * S_ + r) * S_;
    const u16* hrow = heavyIn + ((size_t)h * NSCAN_ + (r - CB_)) * HB_;
    float ls = 0.f;
    for (int i = tid; i < HB_; i += 256) {
        const int col = hrow[i];
        const float p = __expf(bf2f(srow[col]));
        sbuf[i] = p; cbuf[i] = (u16)col;
        ls += p;
    }
    ls = wsum64(ls);
    if (lane == 0) wred[wave] = ls;
    __syncthreads();
    const float Z = wred[0] + wred[1] + wred[2] + wred[3]
                  + rsumG[(size_t)h * NSCAN_ + r - CB_];
    float pv = 0.f;
    const float* vh = V + (size_t)h * S_ * D_;
    for (int i = wave; i < HB_; i += 4)
        pv += sbuf[i] * vh[(size_t)cbuf[i] * D_ + lane];
    opart[wave][lane] = pv;
    __syncthreads();
    if (tid < 64) {
        const float tot = opart[0][tid] + opart[1][tid] + opart[2][tid] + opart[3][tid];
        float* op = &O[(size_t)r * E_ + h * D_ + tid];
        *op = (*op + tot) / Z;
    }
}

// ---------------------------------------------------------------------------
extern "C" void kernel_launch(void* const* d_in, const int* in_sizes, int n_in,
                              void* d_out, int out_size, void* d_ws, size_t ws_size,
                              hipStream_t stream)
{
    const float* hs = (const float*)d_in[0];
    const float* Wq = (const float*)d_in[2];
    const float* bq = (const float*)d_in[3];
    const float* Wk = (const float*)d_in[4];
    const float* bk = (const float*)d_in[5];
    const float* Wv = (const float*)d_in[6];
    const float* bv = (const float*)d_in[7];
    const float* Wo = (const float*)d_in[8];
    const float* bo = (const float*)d_in[9];

    char* ws = (char*)d_ws;
    const size_t MB = 1024 * 1024;
    float* Q     = (float*)(ws);                   //   8 MB [H][S][D]
    float* K     = (float*)(ws + 8 * MB);          //   8 MB
    float* V     = (float*)(ws + 16 * MB);         //   8 MB
    u16*   Sc    = (u16*)  (ws + 24 * MB);         // 128 MB [H][S][S] bf16
    u16*   hvy   = (u16*)  (ws + 152 * MB);        // ~10.2 MB [H][NSCAN][HB]
    float* rsumG = (float*)(ws + 163 * MB);        // 105 KB [H][NSCAN]
    float* accG  = (float*)(ws + 164 * MB);        //  26 KB [H][CB]
    float* O     = (float*)(ws + 168 * MB);        //   8 MB [S][E]
    (void)ws_size; (void)in_sizes; (void)n_in; (void)out_size;

    (void)hipMemsetAsync(accG, 0, (size_t)H_ * CB_ * sizeof(float), stream);
    qkv_gemm<<<dim3(8, 16, 3), 256, 0, stream>>>(hs, Wq, bq, Wk, bk, Wv, bv, Q, K, V);
    sc_gemm <<<dim3(32, 32, 16), 256, 0, stream>>>(Q, K, Sc);
    prep_kernel<<<dim3(NSCAN_ / 4 + CB_ / 4, H_), 256, 0, stream>>>(Sc, rsumG, accG);
    scan_fill<<<16 + NFULL_ + NPART_, 256, 0, stream>>>(Sc, accG, rsumG, hvy, V, O);
    heavy_merge<<<NPART_, 256, 0, stream>>>(Sc, V, hvy, rsumG, O);
    proj_gemm<<<dim3(8, 16, 1), 256, 0, stream>>>(O, Wo, bo, (float*)d_out);
}

// Round 9
// 1469.293 us; speedup vs baseline: 1.3102x; 1.2010x over previous
//
#include <hip/hip_runtime.h>

#define S_ 2048
#define E_ 1024
#define H_ 16
#define D_ 64
#define HB_ 204
#define RB_ 204
#define CB_ 408
#define NSCAN_ (S_ - CB_)
#define PEN_ 0.99f
#define NEGINF (-__builtin_huge_valf())
#define POSINF (__builtin_huge_valf())

typedef unsigned short u16;
typedef unsigned int u32;
typedef unsigned int u32x4 __attribute__((ext_vector_type(4)));

__device__ __forceinline__ float bf2f(u16 u) {
    union { u32 u; float f; } a; a.u = ((u32)u) << 16; return a.f;
}
__device__ __forceinline__ u16 f2bf(float f) {
    union { float f; u32 u; } a; a.f = f;
    u32 r = (a.u + 0x7FFFu + ((a.u >> 16) & 1u)) >> 16;
    return (u16)r;
}

// ---------------------------------------------------------------------------
// Wave64 reductions via DPP.
// ---------------------------------------------------------------------------
#define DPPF(ID, V, CTRL, RMASK) \
    __int_as_float(__builtin_amdgcn_update_dpp(__float_as_int(ID), __float_as_int(V), CTRL, RMASK, 0xf, false))

__device__ __forceinline__ float wsum64_63(float v) {
    float t;
    t = DPPF(0.f, v, 0x111, 0xf); v += t;
    t = DPPF(0.f, v, 0x112, 0xf); v += t;
    t = DPPF(0.f, v, 0x114, 0xf); v += t;
    t = DPPF(0.f, v, 0x118, 0xf); v += t;
    t = DPPF(0.f, v, 0x142, 0xa); v += t;
    t = DPPF(0.f, v, 0x143, 0xc); v += t;
    return v;
}
__device__ __forceinline__ float wsum64(float v) {
    v = wsum64_63(v);
    return __int_as_float(__builtin_amdgcn_readlane(__float_as_int(v), 63));
}
template <int CTRL, int RMASK>
__device__ __forceinline__ double dmin_step(double v) {
    const int lo = __double2loint(v), hi = __double2hiint(v);
    const int slo = __builtin_amdgcn_update_dpp(0, lo, CTRL, RMASK, 0xf, false);
    const int shi = __builtin_amdgcn_update_dpp(0x7FF00000, hi, CTRL, RMASK, 0xf, false);
    return fmin(v, __hiloint2double(shi, slo));
}
__device__ __forceinline__ double wmind64(double v) {
    v = dmin_step<0x111, 0xf>(v);
    v = dmin_step<0x112, 0xf>(v);
    v = dmin_step<0x114, 0xf>(v);
    v = dmin_step<0x118, 0xf>(v);
    v = dmin_step<0x142, 0xa>(v);   // row_bcast15
    v = dmin_step<0x143, 0xc>(v);   // row_bcast31
    return v;                        // lane 63 holds the wave min
}

// ---------------------------------------------------------------------------
// QKV projection: X[S,E] @ W^T + b -> head-major [H][S][D] f32.
// ---------------------------------------------------------------------------
__global__ __launch_bounds__(256) void qkv_gemm(
    const float* __restrict__ X,
    const float* __restrict__ W0, const float* __restrict__ b0,
    const float* __restrict__ W1, const float* __restrict__ b1,
    const float* __restrict__ W2, const float* __restrict__ b2,
    float* __restrict__ Q, float* __restrict__ K, float* __restrict__ V)
{
    const int z = blockIdx.z;
    const float* W    = (z == 0) ? W0 : (z == 1) ? W1 : W2;
    const float* bias = (z == 0) ? b0 : (z == 1) ? b1 : b2;
    float* dst        = (z == 0) ? Q  : (z == 1) ? K  : V;
    const int o0 = blockIdx.x * 128, s0 = blockIdx.y * 128;
    __shared__ float As[16][132];   // [k][m]
    __shared__ float Bs[16][132];   // [k][n]
    const int tid = threadIdx.x;
    const int ty = tid >> 4, tx = tid & 15;
    const int r = tid >> 1, kq = (tid & 1) << 3;
    float acc[8][8] = {};
    for (int kb = 0; kb < E_; kb += 16) {
        float4 a0 = *(const float4*)&X[(size_t)(s0 + r) * E_ + kb + kq];
        float4 a1 = *(const float4*)&X[(size_t)(s0 + r) * E_ + kb + kq + 4];
        float4 w0 = *(const float4*)&W[(size_t)(o0 + r) * E_ + kb + kq];
        float4 w1 = *(const float4*)&W[(size_t)(o0 + r) * E_ + kb + kq + 4];
        __syncthreads();
        As[kq+0][r]=a0.x; As[kq+1][r]=a0.y; As[kq+2][r]=a0.z; As[kq+3][r]=a0.w;
        As[kq+4][r]=a1.x; As[kq+5][r]=a1.y; As[kq+6][r]=a1.z; As[kq+7][r]=a1.w;
        Bs[kq+0][r]=w0.x; Bs[kq+1][r]=w0.y; Bs[kq+2][r]=w0.z; Bs[kq+3][r]=w0.w;
        Bs[kq+4][r]=w1.x; Bs[kq+5][r]=w1.y; Bs[kq+6][r]=w1.z; Bs[kq+7][r]=w1.w;
        __syncthreads();
        #pragma unroll
        for (int kk = 0; kk < 16; ++kk) {
            float av[8], bv[8];
            *(float4*)&av[0] = *(const float4*)&As[kk][ty * 8];
            *(float4*)&av[4] = *(const float4*)&As[kk][ty * 8 + 4];
            *(float4*)&bv[0] = *(const float4*)&Bs[kk][tx * 8];
            *(float4*)&bv[4] = *(const float4*)&Bs[kk][tx * 8 + 4];
            #pragma unroll
            for (int i = 0; i < 8; ++i)
                #pragma unroll
                for (int j = 0; j < 8; ++j) acc[i][j] += av[i] * bv[j];
        }
    }
    #pragma unroll
    for (int i = 0; i < 8; ++i) {
        const int s = s0 + ty * 8 + i;
        #pragma unroll
        for (int jq = 0; jq < 2; ++jq) {
            const int o = o0 + tx * 8 + jq * 4;
            float4 v;
            v.x = acc[i][jq*4+0] + bias[o+0];
            v.y = acc[i][jq*4+1] + bias[o+1];
            v.z = acc[i][jq*4+2] + bias[o+2];
            v.w = acc[i][jq*4+3] + bias[o+3];
            if (z == 0) { v.x *= 0.125f; v.y *= 0.125f; v.z *= 0.125f; v.w *= 0.125f; }
            *(float4*)&dst[((size_t)(o >> 6) * S_ + s) * D_ + (o & 63)] = v;
        }
    }
}

// ---------------------------------------------------------------------------
// Output projection: Y[S,E] = X[S,E] @ Wo^T + bo
// ---------------------------------------------------------------------------
__global__ __launch_bounds__(256) void proj_gemm(
    const float* __restrict__ X, const float* __restrict__ W,
    const float* __restrict__ bias, float* __restrict__ Y)
{
    const int o0 = blockIdx.x * 128, s0 = blockIdx.y * 128;
    __shared__ float As[16][132];
    __shared__ float Bs[16][132];
    const int tid = threadIdx.x;
    const int ty = tid >> 4, tx = tid & 15;
    const int r = tid >> 1, kq = (tid & 1) << 3;
    float acc[8][8] = {};
    for (int kb = 0; kb < E_; kb += 16) {
        float4 a0 = *(const float4*)&X[(size_t)(s0 + r) * E_ + kb + kq];
        float4 a1 = *(const float4*)&X[(size_t)(s0 + r) * E_ + kb + kq + 4];
        float4 w0 = *(const float4*)&W[(size_t)(o0 + r) * E_ + kb + kq];
        float4 w1 = *(const float4*)&W[(size_t)(o0 + r) * E_ + kb + kq + 4];
        __syncthreads();
        As[kq+0][r]=a0.x; As[kq+1][r]=a0.y; As[kq+2][r]=a0.z; As[kq+3][r]=a0.w;
        As[kq+4][r]=a1.x; As[kq+5][r]=a1.y; As[kq+6][r]=a1.z; As[kq+7][r]=a1.w;
        Bs[kq+0][r]=w0.x; Bs[kq+1][r]=w0.y; Bs[kq+2][r]=w0.z; Bs[kq+3][r]=w0.w;
        Bs[kq+4][r]=w1.x; Bs[kq+5][r]=w1.y; Bs[kq+6][r]=w1.z; Bs[kq+7][r]=w1.w;
        __syncthreads();
        #pragma unroll
        for (int kk = 0; kk < 16; ++kk) {
            float av[8], bv[8];
            *(float4*)&av[0] = *(const float4*)&As[kk][ty * 8];
            *(float4*)&av[4] = *(const float4*)&As[kk][ty * 8 + 4];
            *(float4*)&bv[0] = *(const float4*)&Bs[kk][tx * 8];
            *(float4*)&bv[4] = *(const float4*)&Bs[kk][tx * 8 + 4];
            #pragma unroll
            for (int i = 0; i < 8; ++i)
                #pragma unroll
                for (int j = 0; j < 8; ++j) acc[i][j] += av[i] * bv[j];
        }
    }
    #pragma unroll
    for (int i = 0; i < 8; ++i) {
        const int s = s0 + ty * 8 + i;
        #pragma unroll
        for (int jq = 0; jq < 2; ++jq) {
            const int o = o0 + tx * 8 + jq * 4;
            float4 v;
            v.x = acc[i][jq*4+0] + bias[o+0];
            v.y = acc[i][jq*4+1] + bias[o+1];
            v.z = acc[i][jq*4+2] + bias[o+2];
            v.w = acc[i][jq*4+3] + bias[o+3];
            *(float4*)&Y[(size_t)s * E_ + o] = v;
        }
    }
}

// ---------------------------------------------------------------------------
// Sc[h][i][j] = Q[h][i] . K[h][j] (bf16). Lower-tri tiles only. k-major LDS.
// ---------------------------------------------------------------------------
__global__ __launch_bounds__(256) void sc_gemm(const float* __restrict__ Q,
                                               const float* __restrict__ K,
                                               u16* __restrict__ Sc)
{
    const int h = blockIdx.z;
    const int jt = blockIdx.x, it = blockIdx.y;
    if (jt > it) return;
    const int i0 = it * 64, j0 = jt * 64;
    __shared__ float Qs[64][65];   // [k][m]
    __shared__ float Ks[64][65];   // [k][n]
    const float* Qh = Q + (size_t)h * S_ * D_;
    const float* Kh = K + (size_t)h * S_ * D_;
    const int tid = threadIdx.x;
    for (int idx = tid; idx < 1024; idx += 256) {
        const int rr = idx >> 4, c4 = (idx & 15) << 2;
        float4 q4 = *(const float4*)&Qh[(size_t)(i0 + rr) * D_ + c4];
        Qs[c4 + 0][rr] = q4.x; Qs[c4 + 1][rr] = q4.y; Qs[c4 + 2][rr] = q4.z; Qs[c4 + 3][rr] = q4.w;
        float4 k4 = *(const float4*)&Kh[(size_t)(j0 + rr) * D_ + c4];
        Ks[c4 + 0][rr] = k4.x; Ks[c4 + 1][rr] = k4.y; Ks[c4 + 2][rr] = k4.z; Ks[c4 + 3][rr] = k4.w;
    }
    __syncthreads();
    const int ty = tid >> 4, tx = tid & 15;
    float acc[4][4] = {};
    #pragma unroll 4
    for (int kk = 0; kk < 64; ++kk) {
        float4 a4 = *(const float4*)&Qs[kk][ty * 4];
        float4 b4 = *(const float4*)&Ks[kk][tx * 4];
        const float av[4] = {a4.x, a4.y, a4.z, a4.w};
        const float bv[4] = {b4.x, b4.y, b4.z, b4.w};
        #pragma unroll
        for (int i = 0; i < 4; ++i)
            #pragma unroll
            for (int j = 0; j < 4; ++j) acc[i][j] += av[i] * bv[j];
    }
    u16* out = Sc + ((size_t)h * S_ + i0) * S_ + j0;
    #pragma unroll
    for (int i = 0; i < 4; ++i)
        #pragma unroll
        for (int j = 0; j < 4; ++j)
            out[(size_t)(ty * 4 + i) * S_ + tx * 4 + j] = f2bf(acc[i][j]);
}

// ---------------------------------------------------------------------------
// prep_kernel: rsum per scan row + acc-init over rows 0..407 (global atomics).
// ---------------------------------------------------------------------------
__global__ __launch_bounds__(256) void prep_kernel(const u16* __restrict__ Sc,
                                                   float* __restrict__ rsumG,
                                                   float* __restrict__ accG)
{
    const int h = blockIdx.y;
    const int wave = threadIdx.x >> 6, lane = threadIdx.x & 63;
    const int bx = blockIdx.x;
    if (bx < NSCAN_ / 4) {
        const int tok = CB_ + bx * 4 + wave;
        const u16* row = Sc + ((size_t)h * S_ + tok) * S_ + (tok - RB_);
        float sm = 0.f;
        #pragma unroll
        for (int k = 0; k < 4; ++k) {
            const int j = k * 64 + lane;
            if (j <= RB_) sm += __expf(bf2f(row[j]));
        }
        const float z = wsum64(sm);
        if (lane == 0) rsumG[(size_t)h * NSCAN_ + tok - CB_] = z;
    } else {
        const int t = (bx - NSCAN_ / 4) * 4 + wave;   // 0..407
        const u16* row = Sc + ((size_t)h * S_ + t) * S_;
        float sm = 0.f;
        for (int c = lane; c <= t; c += 64) sm += __expf(bf2f(row[c]));
        const float z = wsum64(sm);
        const float w = __powf(PEN_, (float)(CB_ - 1 - t)) / z;
        for (int c = lane; c <= t; c += 64)
            atomicAdd(&accG[h * CB_ + c], __expf(bf2f(row[c])) * w);
    }
}

// ---------------------------------------------------------------------------
// MERGED kernel. R8: PRODUCER-CONSUMER WAVE SPECIALIZATION for the scan.
// Evidence (R0..R7): any scheme where the critical wave also executes the
// bulk work (ring updates, staging) lands at >=900us; the chain alone is
// ~430cy. R8 splits roles:
//   wave0 = CHAIN (R0's proven 4-slot datapath): keys/wmin, gathers/exps/
//           wsum, eviction via readlane, hacc update, hOut, publish invZ.
//           Candidate via R4's register recurrence:
//           accc(k) = ring[li(k-1)]*PEN + ew0_prev*invZ_prev (cell value
//           after k-2, written by helpers in interval k-1).
//   wave1 = STAGER: R0's exact load ledger (loads ONLY in its vm stream ->
//           WAIT_VM counts are exact); stages row k+2 -> buf[(k+2)%4].
//   waves2,3 = RING UPDATERS, lag 1 token: at interval k apply iteration
//           k-1's ring updates for cells s in [1,204] (s=0 skipped: its
//           value IS the chain's accc -> no read/write race on that cell).
//           Need only invZ(k-1) (LDS pub, parity) + row k-1's buffer.
//   One SBAR (lgkmcnt-only) per interval. Buffers k,k-1,k+2 distinct mod 4.
//   Ramp 408..413 runs wholly in wave0 (R0's proven full body, LDS ring,
//   conservative drains); iter 413 skips ring writes (helpers take over at
//   414) and publishes invZ(413)/ew0_prev. All formulas bit-identical to
//   the R0/R4-proven datapaths; only the executor of ring updates changes.
// ---------------------------------------------------------------------------
#define NFULL_ (CB_ * H_)          /* 6528  full-attn blocks (r<CB)  */
#define NPART_ (NSCAN_ * H_)       /* 26240 recent-partial blocks    */

__global__ __launch_bounds__(256) void scan_fill(const u16* __restrict__ Sc,
                                                 const float* __restrict__ accG,
                                                 const float* __restrict__ rsumG,
                                                 u16* __restrict__ heavyOut,
                                                 const float* __restrict__ V,
                                                 float* __restrict__ O)
{
    __shared__ __align__(16) char ldsPool[23984];
    const int bid = blockIdx.x;
    const int tid = threadIdx.x;

    if (bid >= 16) {
        // ---------------- fill paths: dense attention work ----------------
        float* sbuf  = (float*)ldsPool;            // up to 416 f32
        float* wred  = (float*)(ldsPool + 1664);   // 4 f32
        float* opart = (float*)(ldsPool + 1696);   // 256 f32
        const int lane = tid & 63, wave = tid >> 6;
        int h, r, c0, n;
        bool partial;
        if (bid < 16 + NFULL_) {                   // r < CB: full causal row
            const int t2 = bid - 16;
            r = t2 >> 4; h = t2 & 15;
            c0 = 0; n = r + 1; partial = false;
        } else {                                   // r >= CB: recent window only
            const int idx = bid - 16 - NFULL_;
            r = CB_ + (idx >> 4); h = idx & 15;
            c0 = r - RB_; n = RB_ + 1; partial = true;
        }
        const u16* srow = Sc + ((size_t)h * S_ + r) * S_;
        float ls = 0.f;
        for (int i = tid; i < n; i += 256) {
            const float p = __expf(bf2f(srow[c0 + i]));
            sbuf[i] = p; ls += p;
        }
        ls = wsum64(ls);
        if (lane == 0) wred[wave] = ls;
        __syncthreads();
        const float Z = wred[0] + wred[1] + wred[2] + wred[3];
        float pv = 0.f;
        const float* vh = V + (size_t)h * S_ * D_;
        for (int i = wave; i < n; i += 4)
            pv += sbuf[i] * vh[(size_t)(c0 + i) * D_ + lane];
        opart[wave * 64 + lane] = pv;
        __syncthreads();
        if (tid < 64) {
            const float tot = opart[tid] + opart[64 + tid] + opart[128 + tid] + opart[192 + tid];
            // partial rows: store UNNORMALIZED; heavy_merge adds + divides
            O[(size_t)r * E_ + h * D_ + tid] = partial ? tot : (tot / Z);
        }
        return;
    }

    // ---------------- scan path: specialized waves ----------------
    const int h = bid;
    const int lane = tid & 63, wv = tid >> 6;
    float* ring    = (float*)ldsPool;              // 256 f32 (1024 B)
    float* rsumLDS = (float*)(ldsPool + 1024);     // NSCAN f32 (6560 B)
    u16*   buf_0   = (u16*)(ldsPool + 7584);       // 4096 B (rows tok%4==0)
    u16*   buf_1   = (u16*)(ldsPool + 11680);
    u16*   buf_2   = (u16*)(ldsPool + 15776);
    u16*   buf_3   = (u16*)(ldsPool + 19872);
    float* pubL    = (float*)(ldsPool + 23968);    // 2 f32 (invZ parity)
    const u16* sch = Sc + (size_t)h * S_ * S_;
    const float* accH = accG + h * CB_;
    u16* hOutH = heavyOut + (size_t)h * NSCAN_ * HB_;

    if (wv == 0) __builtin_amdgcn_s_setprio(3);

    #define ISSUE_ROW(BUF, ROWI)                                                 \
        do {                                                                     \
            const void* _ap = (const void*)((const char*)(sch + (size_t)(ROWI) * S_) + lane * 16); \
            asm volatile("global_load_dwordx4 %0, %4, off\n\t"                   \
                         "global_load_dwordx4 %1, %4, off offset:1024\n\t"       \
                         "global_load_dwordx4 %2, %4, off offset:2048\n\t"       \
                         "global_load_dwordx4 %3, %4, off offset:3072"           \
                         : "=&v"(BUF[0]), "=&v"(BUF[1]), "=&v"(BUF[2]), "=&v"(BUF[3]) \
                         : "v"(_ap) : "memory");                                 \
        } while (0)
    #define STAGE(BUF, DST)                                                      \
        do {                                                                     \
            u32x4* _db = (u32x4*)(DST);                                          \
            _Pragma("unroll")                                                    \
            for (int _j = 0; _j < 4; ++_j) _db[_j * 64 + lane] = (BUF)[_j];      \
        } while (0)
    #define WAIT_VM(N) asm volatile("s_waitcnt vmcnt(" #N ")" ::: "memory")
    #define SBAR() asm volatile("s_waitcnt lgkmcnt(0)\n\ts_barrier" ::: "memory")

    // persistent chain state (wave0); stager quads (wave1)
    int hcol[4]; float hacc[4];
    float acc_cand = 0.f, ew0_prev = 0.f, invZ_prev = 0.f;
    u32x4 q0[4], q1[4], q2[4], q3[4];   // wave1 row quads (row r -> q[r&3])
    const bool v3 = (lane < (HB_ - 192)) || (lane == 63);

    for (int i = tid; i < NSCAN_; i += 256) rsumLDS[i] = rsumG[(size_t)h * NSCAN_ + i];
    __syncthreads();   // (A) rsum visible

    if (wv == 1) {     // pre-issue steady rows 414..417 (row r -> q[r&3])
        ISSUE_ROW(q2, CB_ + 6);
        ISSUE_ROW(q3, CB_ + 7);
        ISSUE_ROW(q0, CB_ + 8);
        ISSUE_ROW(q1, CB_ + 9);
    }

    if (wv == 0) {
        // ---- ramp: iterations 408..413 entirely in wave0 (R0-proven) ----
        u32x4 r0[4], r1[4], r2[4], r3[4];
        ISSUE_ROW(r0, CB_ + 0);
        ISSUE_ROW(r1, CB_ + 1);
        ISSUE_ROW(r2, CB_ + 2);
        ISSUE_ROW(r3, CB_ + 3);
        for (int c = HB_ + lane; c < CB_; c += 64) ring[c & 255] = accH[c];
        #pragma unroll
        for (int k = 0; k < 4; ++k) {
            const int slot = lane + 64 * k;
            hcol[k] = (slot < HB_) ? slot : 0;
            hacc[k] = (slot < HB_) ? accH[slot] : POSINF;
        }
        WAIT_VM(0);
        STAGE(r0, buf_0); STAGE(r1, buf_1); STAGE(r2, buf_2); STAGE(r3, buf_3);
        ISSUE_ROW(r0, CB_ + 4);   // row 412
        ISSUE_ROW(r1, CB_ + 5);   // row 413

        {   // peeled tok=408 (li=204): no eviction
            const u16* srow = buf_0;
            float e[4]; float lsum = 0.f;
            #pragma unroll
            for (int k = 0; k < 4; ++k) {
                const bool v = (k < 3) || (lane < (HB_ - 192));
                e[k] = v ? __expf(bf2f(srow[hcol[k]])) : 0.f;
                lsum += e[k];
            }
            const float Z = wsum64(lsum) + rsumLDS[0];
            const float invZ = __fdividef(1.f, Z);
            #pragma unroll
            for (int k = 0; k < 4; ++k) hacc[k] = hacc[k] * PEN_ + e[k] * invZ;
            #pragma unroll
            for (int k = 0; k < 4; ++k) {
                const int slot = lane + 64 * k;
                if (slot < HB_) hOutH[slot] = (u16)slot;
            }
            float nv0 = 0.f;
            #pragma unroll
            for (int k = 0; k < 4; ++k) {
                const int slot = lane + 64 * k;
                if (slot <= RB_) {
                    const int col = HB_ + slot;
                    const float p = __expf(bf2f(srow[col])) * invZ;
                    const float old = (col == CB_) ? 0.f : ring[col & 255];
                    const float nv = old * PEN_ + p;
                    ring[col & 255] = nv;
                    if (k == 0) nv0 = nv;
                }
            }
            acc_cand = __int_as_float(__builtin_amdgcn_readlane(__float_as_int(nv0), 0));
        }

        #define RITER(TOK, SBUF, SKIPRING)                                       \
        do {                                                                     \
            const int _t = (TOK), _li = _t - RB_;                                \
            const u16* _sr = (const u16*)(SBUF);                                 \
            if (lane == 63) { hcol[3] = _li - 1; hacc[3] = acc_cand; }           \
            float _pwr[4], _oldw[4];                                             \
            _Pragma("unroll")                                                    \
            for (int _k = 0; _k < 4; ++_k) {                                     \
                const int _slot = lane + 64 * _k;                                \
                if (_slot <= RB_) {                                              \
                    const int _col = _li + _slot;                                \
                    _pwr[_k] = bf2f(_sr[_col]);                                  \
                    _oldw[_k] = (_col == _t) ? 0.f : ring[_col & 255];           \
                } else { _pwr[_k] = NEGINF; _oldw[_k] = 0.f; }                   \
            }                                                                    \
            double _kmin = __hiloint2double(__float_as_int(hacc[0]),             \
                                            ((2047 - hcol[0]) << 8) | lane);     \
            _Pragma("unroll")                                                    \
            for (int _k = 1; _k < 4; ++_k) {                                     \
                const int _slot = lane + 64 * _k;                                \
                _kmin = fmin(_kmin, __hiloint2double(__float_as_int(hacc[_k]),   \
                                        ((2047 - hcol[_k]) << 8) | _slot));      \
            }                                                                    \
            _kmin = wmind64(_kmin);                                              \
            float _e[4]; float _lsum = 0.f;                                      \
            _Pragma("unroll")                                                    \
            for (int _k = 0; _k < 4; ++_k) {                                     \
                const bool _v = (_k < 3) || v3;                                  \
                _e[_k] = _v ? __expf(bf2f(_sr[hcol[_k]])) : 0.f;                 \
                _lsum += _e[_k];                                                 \
            }                                                                    \
            const float _presum = wsum64(_lsum);                                 \
            const int _ev = __builtin_amdgcn_readlane(__double2loint(_kmin), 63) & 255; \
            const int _kb = _ev >> 6;                                            \
            const float _esel = (_kb == 0) ? _e[0] : (_kb == 1) ? _e[1]          \
                              : (_kb == 2) ? _e[2] : _e[3];                      \
            const float _ebc = __int_as_float(__builtin_amdgcn_readlane(         \
                                   __float_as_int(_esel), _ev & 63));            \
            const float _el1 = __int_as_float(__builtin_amdgcn_readlane(         \
                                   __float_as_int(_e[3]), 63));                  \
            const float _Z = _presum - _ebc + rsumLDS[_t - CB_];                 \
            const float _invZ = __fdividef(1.f, _Z);                             \
            _Pragma("unroll")                                                    \
            for (int _k = 0; _k < 4; ++_k) {                                     \
                const int _slot = lane + 64 * _k;                                \
                const bool _m = (_slot == _ev);                                  \
                hcol[_k] = _m ? (_li - 1) : hcol[_k];                            \
                hacc[_k] = (_m ? acc_cand : hacc[_k]) * PEN_                     \
                         + (_m ? _el1 : _e[_k]) * _invZ;                         \
            }                                                                    \
            u16* _hrow = hOutH + (size_t)(_t - CB_) * HB_;                       \
            _Pragma("unroll")                                                    \
            for (int _k = 0; _k < 4; ++_k) {                                     \
                const int _slot = lane + 64 * _k;                                \
                if (_slot < HB_) _hrow[_slot] = (u16)hcol[_k];                   \
            }                                                                    \
            float _nv0 = 0.f;                                                    \
            _Pragma("unroll")                                                    \
            for (int _k = 0; _k < 4; ++_k) {                                     \
                const int _slot = lane + 64 * _k;                                \
                if (_slot <= RB_) {                                              \
                    const float _nv = _oldw[_k] * PEN_ + __expf(_pwr[_k]) * _invZ; \
                    if (!(SKIPRING)) ring[(_li + _slot) & 255] = _nv;            \
                    if (_k == 0) _nv0 = _nv;                                     \
                }                                                                \
            }                                                                    \
            acc_cand = __int_as_float(__builtin_amdgcn_readlane(__float_as_int(_nv0), 0)); \
            if (SKIPRING) {                                                      \
                ew0_prev = __expf(bf2f(_sr[_li]));                               \
                invZ_prev = _invZ;                                               \
                if (lane == 0) pubL[(_t) & 1] = _invZ;                           \
            }                                                                    \
        } while (0)

        WAIT_VM(4);                 // row 412 (r0) done; r1 may be pending
        STAGE(r0, buf_0);
        RITER(CB_ + 1, buf_1, 0);   // 409
        WAIT_VM(0);                 // row 413 done (drains hOut stores too)
        STAGE(r1, buf_1);
        RITER(CB_ + 2, buf_2, 0);   // 410
        RITER(CB_ + 3, buf_3, 0);   // 411
        RITER(CB_ + 4, buf_0, 0);   // 412
        RITER(CB_ + 5, buf_1, 1);   // 413: SKIP ring writes; publish invZ
        #undef RITER
    }

    SBAR();   // (B) ramp done: bufs 0..3 = rows 412,413,410,411; pub[1]=invZ(413)

    if (wv == 1) {
        WAIT_VM(8);                  // rows 414,415 done (rows 416,417 pending)
        STAGE(q2, buf_2);            // row 414 (overwrites row 410: dead)
        STAGE(q3, buf_3);            // row 415 (overwrites row 411: dead)
        ISSUE_ROW(q2, CB_ + 10);     // row 418
        ISSUE_ROW(q3, CB_ + 11);     // row 419
    }

    SBAR();   // (C) steady-state entry: bufs = rows 412,413,414,415

    // ---- steady intervals k = 414..2047 ----
    // chain reads buf[k%4]; helpers read buf[(k-1)%4]; stager -> buf[(k+2)%4].
    #define STEP(K, BC, BH, BS, Q)                                               \
    do {                                                                         \
        const int _K = (K);                                                      \
        if (wv == 0) {                                                           \
            const int _li = _K - RB_;                                            \
            const float _oldr = ring[(_li - 1) & 255];                           \
            acc_cand = _oldr * PEN_ + ew0_prev * invZ_prev;                      \
            if (lane == 63) { hcol[3] = _li - 1; hacc[3] = acc_cand; }           \
            double _kmin = __hiloint2double(__float_as_int(hacc[0]),             \
                                            ((2047 - hcol[0]) << 8) | lane);     \
            _Pragma("unroll")                                                    \
            for (int _k = 1; _k < 4; ++_k) {                                     \
                const int _slot = lane + 64 * _k;                                \
                _kmin = fmin(_kmin, __hiloint2double(__float_as_int(hacc[_k]),   \
                                        ((2047 - hcol[_k]) << 8) | _slot));      \
            }                                                                    \
            _kmin = wmind64(_kmin);                                              \
            const u16* _sr = (const u16*)(BC);                                   \
            float _e[4]; float _lsum = 0.f;                                      \
            _Pragma("unroll")                                                    \
            for (int _k = 0; _k < 4; ++_k) {                                     \
                const bool _v = (_k < 3) || v3;                                  \
                _e[_k] = _v ? __expf(bf2f(_sr[hcol[_k]])) : 0.f;                 \
                _lsum += _e[_k];                                                 \
            }                                                                    \
            const float _ew0 = __expf(bf2f(_sr[_li]));                           \
            const float _presum = wsum64(_lsum);                                 \
            const int _ev = __builtin_amdgcn_readlane(__double2loint(_kmin), 63) & 255; \
            const int _kb = _ev >> 6;                                            \
            const float _esel = (_kb == 0) ? _e[0] : (_kb == 1) ? _e[1]          \
                              : (_kb == 2) ? _e[2] : _e[3];                      \
            const float _ebc = __int_as_float(__builtin_amdgcn_readlane(         \
                                   __float_as_int(_esel), _ev & 63));            \
            const float _el1 = __int_as_float(__builtin_amdgcn_readlane(         \
                                   __float_as_int(_e[3]), 63));                  \
            const float _Z = _presum - _ebc + rsumLDS[_K - CB_];                 \
            const float _invZ = __fdividef(1.f, _Z);                             \
            _Pragma("unroll")                                                    \
            for (int _k = 0; _k < 4; ++_k) {                                     \
                const int _slot = lane + 64 * _k;                                \
                const bool _m = (_slot == _ev);                                  \
                hcol[_k] = _m ? (_li - 1) : hcol[_k];                            \
                hacc[_k] = (_m ? acc_cand : hacc[_k]) * PEN_                     \
                         + (_m ? _el1 : _e[_k]) * _invZ;                         \
            }                                                                    \
            u16* _hrow = hOutH + (size_t)(_K - CB_) * HB_;                       \
            _Pragma("unroll")                                                    \
            for (int _k = 0; _k < 4; ++_k) {                                     \
                const int _slot = lane + 64 * _k;                                \
                if (_slot < HB_) _hrow[_slot] = (u16)hcol[_k];                   \
            }                                                                    \
            if (lane == 0) pubL[_K & 1] = _invZ;                                 \
            ew0_prev = _ew0; invZ_prev = _invZ;                                  \
        } else if (wv == 1) {                                                    \
            if (_K + 2 <= S_ - 1) {                                              \
                if (_K <= S_ - 6)      { WAIT_VM(12); }                          \
                else if (_K == S_ - 5) { WAIT_VM(8); }                           \
                else if (_K == S_ - 4) { WAIT_VM(4); }                           \
                else                   { WAIT_VM(0); }                           \
                STAGE(Q, BS);                                                    \
                if (_K + 6 <= S_ - 1) ISSUE_ROW(Q, _K + 6);                      \
            }                                                                    \
        } else {                                                                 \
            const int _j = _K - 1, _lij = _j - RB_;                              \
            const float _invZj = pubL[_j & 1];                                   \
            const u16* _rj = (const u16*)(BH);                                   \
            _Pragma("unroll")                                                    \
            for (int _k2 = 0; _k2 < 2; ++_k2) {                                  \
                const int _s = (wv - 2) * 128 + lane + 64 * _k2;                 \
                if (_s >= 1 && _s <= RB_) {                                      \
                    const int _c = _lij + _s;                                    \
                    const float _old = (_s == RB_) ? 0.f : ring[_c & 255];       \
                    ring[_c & 255] = _old * PEN_ + __expf(bf2f(_rj[_c])) * _invZj; \
                }                                                                \
            }                                                                    \
        }                                                                        \
        SBAR();                                                                  \
    } while (0)

    for (int k0 = CB_ + 6; k0 + 3 <= S_ - 3; k0 += 4) {   // 414..2045 (k0%4==2)
        STEP(k0 + 0, buf_2, buf_1, buf_0, q0);
        STEP(k0 + 1, buf_3, buf_2, buf_1, q1);
        STEP(k0 + 2, buf_0, buf_3, buf_2, q2);
        STEP(k0 + 3, buf_1, buf_0, buf_3, q3);
    }
    STEP(S_ - 2, buf_2, buf_1, buf_0, q0);   // 2046 (no stage)
    STEP(S_ - 1, buf_3, buf_2, buf_1, q1);   // 2047 (no stage)
    #undef STEP
    #undef ISSUE_ROW
    #undef STAGE
    #undef WAIT_VM
    #undef SBAR
}

// ---------------------------------------------------------------------------
// heavy_merge: rows r>=CB. Gather 204 heavy cols, add to the recent-window
// partial already in O, normalize by (heavy sum + rsumG).
// ---------------------------------------------------------------------------
__global__ __launch_bounds__(256) void heavy_merge(const u16* __restrict__ Sc,
                                                   const float* __restrict__ V,
                                                   const u16* __restrict__ heavyIn,
                                                   const float* __restrict__ rsumG,
                                                   float* __restrict__ O)
{
    const int idx = blockIdx.x;
    const int r = CB_ + (idx >> 4), h = idx & 15;
    const int tid = threadIdx.x;
    const int lane = tid & 63, wave = tid >> 6;
    __shared__ float sbuf[208];
    __shared__ u16 cbuf[208];
    __shared__ float wred[4];
    __shared__ float opart[4][64];
    const u16* srow = Sc + ((size_t)h * S_ + r) * S_;
    const u16* hrow = heavyIn + ((size_t)h * NSCAN_ + (r - CB_)) * HB_;
    float ls = 0.f;
    for (int i = tid; i < HB_; i += 256) {
        const int col = hrow[i];
        const float p = __expf(bf2f(srow[col]));
        sbuf[i] = p; cbuf[i] = (u16)col;
        ls += p;
    }
    ls = wsum64(ls);
    if (lane == 0) wred[wave] = ls;
    __syncthreads();
    const float Z = wred[0] + wred[1] + wred[2] + wred[3]
                  + rsumG[(size_t)h * NSCAN_ + r - CB_];
    float pv = 0.f;
    const float* vh = V + (size_t)h * S_ * D_;
    for (int i = wave; i < HB_; i += 4)
        pv += sbuf[i] * vh[(size_t)cbuf[i] * D_ + lane];
    opart[wave][lane] = pv;
    __syncthreads();
    if (tid < 64) {
        const float tot = opart[0][tid] + opart[1][tid] + opart[2][tid] + opart[3][tid];
        float* op = &O[(size_t)r * E_ + h * D_ + tid];
        *op = (*op + tot) / Z;
    }
}

// ---------------------------------------------------------------------------
extern "C" void kernel_launch(void* const* d_in, const int* in_sizes, int n_in,
                              void* d_out, int out_size, void* d_ws, size_t ws_size,
                              hipStream_t stream)
{
    const float* hs = (const float*)d_in[0];
    const float* Wq = (const float*)d_in[2];
    const float* bq = (const float*)d_in[3];
    const float* Wk = (const float*)d_in[4];
    const float* bk = (const float*)d_in[5];
    const float* Wv = (const float*)d_in[6];
    const float* bv = (const float*)d_in[7];
    const float* Wo = (const float*)d_in[8];
    const float* bo = (const float*)d_in[9];

    char* ws = (char*)d_ws;
    const size_t MB = 1024 * 1024;
    float* Q     = (float*)(ws);                   //   8 MB [H][S][D]
    float* K     = (float*)(ws + 8 * MB);          //   8 MB
    float* V     = (float*)(ws + 16 * MB);         //   8 MB
    u16*   Sc    = (u16*)  (ws + 24 * MB);         // 128 MB [H][S][S] bf16
    u16*   hvy   = (u16*)  (ws + 152 * MB);        // ~10.2 MB [H][NSCAN][HB]
    float* rsumG = (float*)(ws + 163 * MB);        // 105 KB [H][NSCAN]
    float* accG  = (float*)(ws + 164 * MB);        //  26 KB [H][CB]
    float* O     = (float*)(ws + 168 * MB);        //   8 MB [S][E]
    (void)ws_size; (void)in_sizes; (void)n_in; (void)out_size;

    (void)hipMemsetAsync(accG, 0, (size_t)H_ * CB_ * sizeof(float), stream);
    qkv_gemm<<<dim3(8, 16, 3), 256, 0, stream>>>(hs, Wq, bq, Wk, bk, Wv, bv, Q, K, V);
    sc_gemm <<<dim3(32, 32, 16), 256, 0, stream>>>(Q, K, Sc);
    prep_kernel<<<dim3(NSCAN_ / 4 + CB_ / 4, H_), 256, 0, stream>>>(Sc, rsumG, accG);
    scan_fill<<<16 + NFULL_ + NPART_, 256, 0, stream>>>(Sc, accG, rsumG, hvy, V, O);
    heavy_merge<<<NPART_, 256, 0, stream>>>(Sc, V, hvy, rsumG, O);
    proj_gemm<<<dim3(8, 16, 1), 256, 0, stream>>>(O, Wo, bo, (float*)d_out);
}